// Round 2
// baseline (826.980 us; speedup 1.0000x reference)
//
#include <hip/hip_runtime.h>

typedef float f32x4 __attribute__((ext_vector_type(4)));
typedef short short8 __attribute__((ext_vector_type(8)));

#define SEQ   1024
#define BB    64
#define VOCAB 32000

// ---------- helpers ----------
__device__ __forceinline__ unsigned short f2bf(float f){
  union { float f; unsigned u; } v; v.f = f;
  unsigned r = v.u + 0x7FFFu + ((v.u >> 16) & 1u);   // RNE
  return (unsigned short)(r >> 16);
}
__device__ __forceinline__ unsigned pk2(float a, float b){
  return (unsigned)f2bf(a) | ((unsigned)f2bf(b) << 16);
}
__device__ __forceinline__ float tanh_fast(float x){
  float a = fminf(fmaxf(x, -15.f), 15.f);
  float e = __expf(2.f * a);
  return (e - 1.f) / (e + 1.f);
}
__device__ __forceinline__ float sigm(float x){ return 1.f / (1.f + expf(-x)); }

__device__ __forceinline__ void ld4(float4* dst, const float* p){
  const float4* q = (const float4*)p;
  dst[0]=q[0]; dst[1]=q[1]; dst[2]=q[2]; dst[3]=q[3];
}
// store 16 floats (as bf16) to LDS row with XOR swizzle (128B rows)
__device__ __forceinline__ void cvt_store(char* base, int row, int kb0, const float4* f){
  int xs = (row & 7) << 4;
  uint4 u;
  u.x = pk2(f[0].x, f[0].y); u.y = pk2(f[0].z, f[0].w);
  u.z = pk2(f[1].x, f[1].y); u.w = pk2(f[1].z, f[1].w);
  *(uint4*)(base + row*128 + (kb0 ^ xs)) = u;
  u.x = pk2(f[2].x, f[2].y); u.y = pk2(f[2].z, f[2].w);
  u.z = pk2(f[3].x, f[3].y); u.w = pk2(f[3].z, f[3].w);
  *(uint4*)(base + row*128 + ((kb0 + 16) ^ xs)) = u;
}

// ---------- phase 1: fused score GEMM ----------
// scores[b][s] += sum_n v[n]*tanh( enc[s,b,:]·U[n,:] + Ub[n] + wq[b][n] )   for s < m
__global__ __launch_bounds__(256, 2)
void score_gemm(const float* __restrict__ enc, const float* __restrict__ Uw,
                const float* __restrict__ Ub, const float* __restrict__ vw,
                const float* __restrict__ wqm, const int* __restrict__ maskp,
                float* __restrict__ scores)
{
  __shared__ char smem[65536];           // 2 bufs x (A 16KB + B 16KB)
  int m = *maskp; m = m < 0 ? 0 : (m > SEQ ? SEQ : m);
  int cx = blockIdx.x & 7, jj = blockIdx.x >> 3;
  int mtile = (jj & ~7) | cx;            // XCD-interleaved mtiles
  int ntile = jj & 7;
  if (mtile * 2 >= m) return;            // fully masked -> skip
  int row0 = mtile * 128;
  int t = threadIdx.x, lane = t & 63;
  int wid = t >> 6, wm = wid >> 1, wn = wid & 1;
  int srow = t >> 2;
  int sk4 = (t & 3) << 4;                // float offset in 64-wide K-step
  int kb0 = (t & 3) << 5;                // byte offset in 128B LDS row

  const float* Ag0 = enc + (size_t)(row0 + srow) * 1024 + sk4;
  const float* Ag1 = Ag0 + 64 * 1024;
  const float* Bg0 = Uw  + (size_t)(ntile * 128 + srow) * 1024 + sk4;
  const float* Bg1 = Bg0 + 64 * 1024;

  float4 fa0[4], fa1[4], fb0[4], fb1[4];

  int aAddr[4], bAddr[4], aXor[4], bXor[4];
  #pragma unroll
  for (int i = 0; i < 4; ++i){
    int ra = wm*64 + i*16 + (lane & 15);
    aAddr[i] = ra * 128; aXor[i] = (ra & 7) << 4;
    int rb = wn*64 + i*16 + (lane & 15);
    bAddr[i] = rb * 128; bXor[i] = (rb & 7) << 4;
  }
  int klane = (lane >> 4) << 4;          // byte offset of this lane's 8-bf16 group

  f32x4 acc[4][4] = {};

  // prologue: load + store K-step 0
  ld4(fa0, Ag0); ld4(fa1, Ag1); ld4(fb0, Bg0); ld4(fb1, Bg1);
  {
    char* bA = smem; char* bB = smem + 16384;
    cvt_store(bA, srow,      kb0, fa0);
    cvt_store(bA, srow + 64, kb0, fa1);
    cvt_store(bB, srow,      kb0, fb0);
    cvt_store(bB, srow + 64, kb0, fb1);
  }

  #pragma unroll 2
  for (int ks = 0; ks < 16; ++ks){
    int buf = ks & 1;
    if (ks < 15){
      int ko = (ks + 1) * 64;
      ld4(fa0, Ag0 + ko); ld4(fa1, Ag1 + ko);
      ld4(fb0, Bg0 + ko); ld4(fb1, Bg1 + ko);
    }
    __syncthreads();
    {
      char* bA = smem + buf * 32768;
      char* bB = bA + 16384;
      #pragma unroll
      for (int kk = 0; kk < 2; ++kk){
        short8 af[4], bv[4];
        int kb = kk * 64 + klane;
        #pragma unroll
        for (int i = 0; i < 4; ++i){
          af[i] = *(const short8*)(bA + aAddr[i] + (kb ^ aXor[i]));
          bv[i] = *(const short8*)(bB + bAddr[i] + (kb ^ bXor[i]));
        }
        #pragma unroll
        for (int mi = 0; mi < 4; ++mi)
          #pragma unroll
          for (int ni = 0; ni < 4; ++ni)
            acc[mi][ni] = __builtin_amdgcn_mfma_f32_16x16x32_bf16(af[mi], bv[ni], acc[mi][ni], 0, 0, 0);
      }
    }
    if (ks < 15){
      int nb = buf ^ 1;
      char* bA = smem + nb * 32768; char* bB = bA + 16384;
      cvt_store(bA, srow,      kb0, fa0);
      cvt_store(bA, srow + 64, kb0, fa1);
      cvt_store(bB, srow,      kb0, fb0);
      cvt_store(bB, srow + 64, kb0, fb1);
    }
  }

  // epilogue: uh -> tanh -> *v -> reduce over 64 cols of this wave -> atomic
  int s_idx = mtile * 2 + wm;            // each wave covers exactly one s (64 rows = 64 b)
  if (s_idx < m){
    float ubv[4], vwv[4];
    #pragma unroll
    for (int ni = 0; ni < 4; ++ni){
      int nt = ntile*128 + wn*64 + ni*16 + (lane & 15);
      ubv[ni] = Ub[nt]; vwv[ni] = vw[nt];
    }
    #pragma unroll
    for (int mi = 0; mi < 4; ++mi){
      #pragma unroll
      for (int j = 0; j < 4; ++j){
        int b = mi*16 + ((lane >> 4) << 2) + j;   // C-row = (lane>>4)*4+reg
        const float* wqrow = wqm + b * 1024;
        float asum = 0.f;
        #pragma unroll
        for (int ni = 0; ni < 4; ++ni){
          int nt = ntile*128 + wn*64 + ni*16 + (lane & 15);
          float uh = acc[mi][ni][j] + ubv[ni] + wqrow[nt];
          asum += tanh_fast(uh) * vwv[ni];
        }
        asum += __shfl_xor(asum, 1, 64);
        asum += __shfl_xor(asum, 2, 64);
        asum += __shfl_xor(asum, 4, 64);
        asum += __shfl_xor(asum, 8, 64);
        if ((lane & 15) == 0)
          atomicAdd(scores + b * 1024 + s_idx, asum);
      }
    }
  }
}

// ---------- generic small GEMM: C[64,N] = A[64,K] @ B[N,K]^T (+bias), bf16 MFMA ----------
// double-buffered LDS, one __syncthreads per 32-wide K-step
__global__ __launch_bounds__(256)
void gemm_m64(const float* __restrict__ A, const float* __restrict__ Bw,
              const float* __restrict__ bias, float* __restrict__ C,
              int N, int K, int stepsPerZ)
{
  __shared__ unsigned short sA[2][64 * 40];    // pad 32->40 (80B rows, 16B aligned)
  __shared__ unsigned short sB[2][128 * 40];
  int t = threadIdx.x, lane = t & 63, wid = t >> 6;
  int ntile = blockIdx.x, z = blockIdx.z;
  int arow = t >> 2, ak = (t & 3) * 8;      // A: 8 floats/thread
  int brow = t >> 1, bk = (t & 1) * 16;     // B: 16 floats/thread
  const float* Ap = A + (size_t)arow * K + ak + (size_t)z * stepsPerZ * 32;
  const float* Bp = Bw + (size_t)(ntile * 128 + brow) * K + bk + (size_t)z * stepsPerZ * 32;
  int klane = (lane >> 4) << 4;             // frag byte offset
  f32x4 acc[4][2] = {};
  float4 a0, a1, b0, b1, b2, b3;

  // prologue: load + store step 0
  {
    const float4* pa = (const float4*)Ap;
    a0 = pa[0]; a1 = pa[1];
    const float4* pb = (const float4*)Bp;
    b0 = pb[0]; b1 = pb[1]; b2 = pb[2]; b3 = pb[3];
    uint4 u;
    u.x = pk2(a0.x,a0.y); u.y = pk2(a0.z,a0.w);
    u.z = pk2(a1.x,a1.y); u.w = pk2(a1.z,a1.w);
    *(uint4*)((char*)sA[0] + arow*80 + ak*2) = u;
    u.x = pk2(b0.x,b0.y); u.y = pk2(b0.z,b0.w);
    u.z = pk2(b1.x,b1.y); u.w = pk2(b1.z,b1.w);
    *(uint4*)((char*)sB[0] + brow*80 + bk*2) = u;
    u.x = pk2(b2.x,b2.y); u.y = pk2(b2.z,b2.w);
    u.z = pk2(b3.x,b3.y); u.w = pk2(b3.z,b3.w);
    *(uint4*)((char*)sB[0] + brow*80 + bk*2 + 16) = u;
  }

  for (int ks = 0; ks < stepsPerZ; ++ks){
    int buf = ks & 1;
    if (ks + 1 < stepsPerZ){
      int kg = (ks + 1) * 32;
      const float4* pa = (const float4*)(Ap + kg);
      a0 = pa[0]; a1 = pa[1];
      const float4* pb = (const float4*)(Bp + kg);
      b0 = pb[0]; b1 = pb[1]; b2 = pb[2]; b3 = pb[3];
    }
    __syncthreads();
    {
      short8 af[4], bv[2];
      #pragma unroll
      for (int mi = 0; mi < 4; ++mi)
        af[mi] = *(const short8*)((char*)sA[buf] + (mi*16 + (lane & 15))*80 + klane);
      #pragma unroll
      for (int ni = 0; ni < 2; ++ni)
        bv[ni] = *(const short8*)((char*)sB[buf] + (wid*32 + ni*16 + (lane & 15))*80 + klane);
      #pragma unroll
      for (int mi = 0; mi < 4; ++mi)
        #pragma unroll
        for (int ni = 0; ni < 2; ++ni)
          acc[mi][ni] = __builtin_amdgcn_mfma_f32_16x16x32_bf16(af[mi], bv[ni], acc[mi][ni], 0, 0, 0);
    }
    if (ks + 1 < stepsPerZ){
      int nb = buf ^ 1;
      uint4 u;
      u.x = pk2(a0.x,a0.y); u.y = pk2(a0.z,a0.w);
      u.z = pk2(a1.x,a1.y); u.w = pk2(a1.z,a1.w);
      *(uint4*)((char*)sA[nb] + arow*80 + ak*2) = u;
      u.x = pk2(b0.x,b0.y); u.y = pk2(b0.z,b0.w);
      u.z = pk2(b1.x,b1.y); u.w = pk2(b1.z,b1.w);
      *(uint4*)((char*)sB[nb] + brow*80 + bk*2) = u;
      u.x = pk2(b2.x,b2.y); u.y = pk2(b2.z,b2.w);
      u.z = pk2(b3.x,b3.y); u.w = pk2(b3.z,b3.w);
      *(uint4*)((char*)sB[nb] + brow*80 + bk*2 + 16) = u;
    }
  }

  bool multi = (gridDim.z > 1);
  #pragma unroll
  for (int ni = 0; ni < 2; ++ni){
    int cg = ntile*128 + wid*32 + ni*16 + (lane & 15);
    float bz = 0.f;
    if (bias && (!multi || z == 0)) bz = bias[cg];
    #pragma unroll
    for (int mi = 0; mi < 4; ++mi){
      int r0 = mi*16 + ((lane >> 4) << 2);
      #pragma unroll
      for (int j = 0; j < 4; ++j){
        float val = acc[mi][ni][j] + bz;
        int off = (r0 + j) * N + cg;
        if (multi) atomicAdd(C + off, val);
        else       C[off] = val;
      }
    }
  }
}

// ---------- softmax over S (masked scores) -> attn output ----------
__global__ __launch_bounds__(256)
void softmax_attn(const float* __restrict__ scores, const float* __restrict__ vb,
                  const int* __restrict__ maskp, float* __restrict__ attn)
{
  __shared__ float sb[4];
  int b = blockIdx.x, t = threadIdx.x, lane = t & 63, wid = t >> 6;
  int m = *maskp; m = m < 0 ? 0 : (m > SEQ ? SEQ : m);
  float vb0 = vb[0];
  float v[4]; float mx = -1e30f;
  #pragma unroll
  for (int k = 0; k < 4; ++k){
    int s = t + k * 256;
    float x = (s < m) ? scores[b*1024 + s] + vb0 : 0.f;
    v[k] = x; mx = fmaxf(mx, x);
  }
  for (int d = 1; d < 64; d <<= 1) mx = fmaxf(mx, __shfl_xor(mx, d, 64));
  if (lane == 0) sb[wid] = mx;
  __syncthreads();
  mx = fmaxf(fmaxf(sb[0], sb[1]), fmaxf(sb[2], sb[3]));
  float sum = 0.f;
  #pragma unroll
  for (int k = 0; k < 4; ++k){ v[k] = expf(v[k] - mx); sum += v[k]; }
  for (int d = 1; d < 64; d <<= 1) sum += __shfl_xor(sum, d, 64);
  __syncthreads();
  if (lane == 0) sb[wid] = sum;
  __syncthreads();
  sum = sb[0] + sb[1] + sb[2] + sb[3];
  #pragma unroll
  for (int k = 0; k < 4; ++k) attn[b*1024 + t + k*256] = v[k] / sum;
}

// ---------- ctx = attn @ enc_out, atomically accumulated into xcat[:,512:1536] ----------
__global__ __launch_bounds__(256)
void ctx_atomic(const float* __restrict__ attn, const float* __restrict__ enc,
                float* __restrict__ xcat)
{
  int b = blockIdx.x >> 4, ch = blockIdx.x & 15;
  int t = threadIdx.x;
  __shared__ float a_s[64];
  if (t < 64) a_s[t] = attn[b*1024 + ch*64 + t];
  __syncthreads();
  const float* ep = enc + (size_t)(ch * 64) * 65536 + b * 1024 + t * 4;
  f32x4 acc = {};
  for (int s2 = 0; s2 < 64; ++s2){
    f32x4 v = *(const f32x4*)(ep + (size_t)s2 * 65536);
    acc += a_s[s2] * v;
  }
  float* dst = xcat + (size_t)b * 1536 + 512 + t * 4;
  atomicAdd(dst + 0, acc.x);
  atomicAdd(dst + 1, acc.y);
  atomicAdd(dst + 2, acc.z);
  atomicAdd(dst + 3, acc.w);
}

__global__ __launch_bounds__(128)
void copy_py(const float* __restrict__ py, float* __restrict__ xcat)
{
  int b = blockIdx.x, t = threadIdx.x;
  *(f32x4*)(xcat + (size_t)b*1536 + t*4) = *(const f32x4*)(py + (size_t)b*512 + t*4);
}

// ---------- GRU elementwise ----------
__global__ __launch_bounds__(256)
void gru_kernel(const float* __restrict__ gi, const float* __restrict__ gh,
                const float* __restrict__ h, float* __restrict__ hnew)
{
  int idx = blockIdx.x * 256 + threadIdx.x;
  int b = idx >> 10, i = idx & 1023;
  const float* gib = gi + b*3072; const float* ghb = gh + b*3072;
  float r = sigm(gib[i] + ghb[i]);
  float z = sigm(gib[1024 + i] + ghb[1024 + i]);
  float n = tanhf(gib[2048 + i] + r * ghb[2048 + i]);
  hnew[idx] = (1.f - z) * n + z * h[idx];
}

// ---------- log_softmax in-place over V ----------
__global__ __launch_bounds__(1024)
void logsoftmax_kernel(float* __restrict__ logits)
{
  __shared__ float sb[16];
  int b = blockIdx.x, t = threadIdx.x, lane = t & 63, wid = t >> 6;
  float* row = logits + (size_t)b * VOCAB;
  float v[32]; float mx = -1e30f;
  #pragma unroll
  for (int k = 0; k < 32; ++k){
    int idx = t + k * 1024;
    if (idx < VOCAB){ v[k] = row[idx]; mx = fmaxf(mx, v[k]); }
    else v[k] = -1e30f;
  }
  for (int d = 1; d < 64; d <<= 1) mx = fmaxf(mx, __shfl_xor(mx, d, 64));
  if (lane == 0) sb[wid] = mx;
  __syncthreads();
  float m2 = -1e30f;
  for (int i = 0; i < 16; ++i) m2 = fmaxf(m2, sb[i]);
  mx = m2;
  float sum = 0.f;
  #pragma unroll
  for (int k = 0; k < 32; ++k){
    int idx = t + k * 1024;
    if (idx < VOCAB) sum += expf(v[k] - mx);
  }
  for (int d = 1; d < 64; d <<= 1) sum += __shfl_xor(sum, d, 64);
  __syncthreads();
  if (lane == 0) sb[wid] = sum;
  __syncthreads();
  float s2 = 0.f;
  for (int i = 0; i < 16; ++i) s2 += sb[i];
  float lse = mx + logf(s2);
  #pragma unroll
  for (int k = 0; k < 32; ++k){
    int idx = t + k * 1024;
    if (idx < VOCAB) row[idx] = v[k] - lse;
  }
}

// ---------- launcher ----------
extern "C" void kernel_launch(void* const* d_in, const int* in_sizes, int n_in,
                              void* d_out, int out_size, void* d_ws, size_t ws_size,
                              hipStream_t stream)
{
  const float* prev_y = (const float*)d_in[0];
  const float* prev_h = (const float*)d_in[1];   // [64,1024]
  const float* enc    = (const float*)d_in[2];   // [1024,64,1024]
  const float* U_w    = (const float*)d_in[3];
  const float* U_b    = (const float*)d_in[4];
  const float* W_w    = (const float*)d_in[5];
  const float* W_b    = (const float*)d_in[6];
  const float* v_w    = (const float*)d_in[7];
  const float* v_b    = (const float*)d_in[8];
  const float* Wc_w   = (const float*)d_in[9];
  const float* Wc_b   = (const float*)d_in[10];
  const float* W_ih   = (const float*)d_in[11];
  const float* W_hh   = (const float*)d_in[12];
  const float* b_ih   = (const float*)d_in[13];
  const float* b_hh   = (const float*)d_in[14];
  const float* Wout_w = (const float*)d_in[15];
  const float* Wout_b = (const float*)d_in[16];
  const int*   maskp  = (const int*)d_in[17];

  float* ws     = (float*)d_ws;
  float* scores = ws;              // 65536  [b][s]
  float* wq     = ws + 65536;      // 65536  [b][a]
  float* xcat   = ws + 131072;     // 98304  [b][1536]  (ctx accumulated into [:,512:])
  float* xvec   = ws + 229376;     // 65536
  float* gi     = ws + 294912;     // 196608
  float* gh     = ws + 491520;     // 196608
  // total ws use: 688128 floats = 2.75 MB

  float* out_logp = (float*)d_out;            // [64,32000]
  float* out_h    = out_logp + 64 * VOCAB;    // [64,1024]
  float* out_attn = out_h + 65536;            // [64,1024]

  // zero atomic-accumulated regions (scores, wq, xcat, xvec, gi, gh)
  hipMemsetAsync(d_ws, 0, (size_t)688128 * sizeof(float), stream);

  // wq = prev_h @ W_w^T + W_b
  gemm_m64<<<dim3(8, 1, 8), 256, 0, stream>>>(prev_h, W_w, W_b, wq, 1024, 1024, 4);
  // fused score GEMM (only s < mask tiles do work)
  score_gemm<<<4096, 256, 0, stream>>>(enc, U_w, U_b, v_w, wq, maskp, scores);
  // softmax -> attn output
  softmax_attn<<<64, 256, 0, stream>>>(scores, v_b, maskp, out_attn);
  // ctx accumulated directly into xcat[:,512:1536]; prev_y copied into xcat[:,0:512]
  ctx_atomic<<<1024, 256, 0, stream>>>(out_attn, enc, xcat);
  copy_py<<<64, 128, 0, stream>>>(prev_y, xcat);
  // x = xcat @ Wc^T + b
  gemm_m64<<<dim3(8, 1, 8), 256, 0, stream>>>(xcat, Wc_w, Wc_b, xvec, 1024, 1536, 6);
  // GRU gates
  gemm_m64<<<dim3(24, 1, 8), 256, 0, stream>>>(xvec, W_ih, b_ih, gi, 3072, 1024, 4);
  gemm_m64<<<dim3(24, 1, 8), 256, 0, stream>>>(prev_h, W_hh, b_hh, gh, 3072, 1024, 4);
  gru_kernel<<<256, 256, 0, stream>>>(gi, gh, prev_h, out_h);
  // logits into d_out, then in-place log_softmax
  gemm_m64<<<dim3(250, 1, 1), 256, 0, stream>>>(out_h, Wout_w, Wout_b, out_logp, VOCAB, 1024, 32);
  logsoftmax_kernel<<<64, 1024, 0, stream>>>(out_logp);
}

// Round 6
// 806.334 us; speedup vs baseline: 1.0256x; 1.0256x over previous
//
#include <hip/hip_runtime.h>

typedef float f32x4 __attribute__((ext_vector_type(4)));
typedef short short8 __attribute__((ext_vector_type(8)));
typedef unsigned int u32;

#define SEQ   1024
#define VOCAB 32000

// ---------- helpers ----------
__device__ __forceinline__ unsigned short f2bf(float f){
  union { float f; unsigned u; } v; v.f = f;
  unsigned r = v.u + 0x7FFFu + ((v.u >> 16) & 1u);   // RNE
  return (unsigned short)(r >> 16);
}
__device__ __forceinline__ unsigned pk2(float a, float b){
  return (unsigned)f2bf(a) | ((unsigned)f2bf(b) << 16);
}
__device__ __forceinline__ float bf2f(unsigned short h){
  union { unsigned u; float f; } v; v.u = ((unsigned)h) << 16; return v.f;
}
__device__ __forceinline__ float tanh_fast(float x){
  float a = fminf(fmaxf(x, -15.f), 15.f);
  float e = __expf(2.f * a);
  return (e - 1.f) / (e + 1.f);
}
__device__ __forceinline__ float sigm(float x){ return 1.f / (1.f + expf(-x)); }

__device__ __forceinline__ void ld4(float4* dst, const float* p){
  const float4* q = (const float4*)p;
  dst[0]=q[0]; dst[1]=q[1]; dst[2]=q[2]; dst[3]=q[3];
}
__device__ __forceinline__ void cvt_store(char* base, int row, int kb0, const float4* f){
  int xs = (row & 7) << 4;
  uint4 u;
  u.x = pk2(f[0].x, f[0].y); u.y = pk2(f[0].z, f[0].w);
  u.z = pk2(f[1].x, f[1].y); u.w = pk2(f[1].z, f[1].w);
  *(uint4*)(base + row*128 + (kb0 ^ xs)) = u;
  u.x = pk2(f[2].x, f[2].y); u.y = pk2(f[2].z, f[2].w);
  u.z = pk2(f[3].x, f[3].y); u.w = pk2(f[3].z, f[3].w);
  *(uint4*)(base + row*128 + ((kb0 + 16) ^ xs)) = u;
}
// async global(16B) -> LDS, wave-uniform LDS base + lane*16
__device__ __forceinline__ void gload_lds16(const void* g, void* l){
  __builtin_amdgcn_global_load_lds((const __attribute__((address_space(1))) u32*)g,
                                   (__attribute__((address_space(3))) u32*)l, 16, 0, 0);
}

// ---------- convert U_w (1M) + enc (64M) fp32 -> bf16 ----------
__global__ __launch_bounds__(256)
void convert_all(const float* __restrict__ uw, const float* __restrict__ enc,
                 unsigned short* __restrict__ uwb, unsigned short* __restrict__ encb)
{
  const int UWC = 131072;                 // 1M/8 chunks
  const int TOT = UWC + 8388608;          // + 64M/8 chunks
  int stride = gridDim.x * 256;
  for (int c = blockIdx.x*256 + threadIdx.x; c < TOT; c += stride){
    const float* src; unsigned short* dst;
    if (c < UWC){ src = uw + (size_t)c*8;        dst = uwb + (size_t)c*8; }
    else        { size_t e = (size_t)(c-UWC)*8;  src = enc + e; dst = encb + e; }
    float4 f0 = ((const float4*)src)[0], f1 = ((const float4*)src)[1];
    uint4 u;
    u.x = pk2(f0.x,f0.y); u.y = pk2(f0.z,f0.w);
    u.z = pk2(f1.x,f1.y); u.w = pk2(f1.z,f1.w);
    *(uint4*)dst = u;
  }
}

// ---------- fused score GEMM (bf16 inputs, global_load_lds) ----------
// scores_part[nt*2+wn][s][b] = partial of v·tanh(uh + Ub + wq) over this block's 64 A-cols
__global__ __launch_bounds__(256)
void score_gemm_bf16(const unsigned short* __restrict__ encb,
                     const unsigned short* __restrict__ uwb,
                     const float* __restrict__ Ub, const float* __restrict__ vw,
                     const float* __restrict__ wqm, const int* __restrict__ maskp,
                     float* __restrict__ scores_part)
{
  __shared__ char smem[32768];           // A 16KB + B 16KB, single buffer
  int m = *maskp; m = m < 0 ? 0 : (m > SEQ ? SEQ : m);
  int bI = blockIdx.x;
  int mtile = bI & 511, ntile = bI >> 9; // same mtile -> same XCD (stride 512 ≡ 0 mod 8)
  if (mtile * 2 >= m) return;
  int t = threadIdx.x, lane = t & 63, wid = t >> 6;
  int wm = wid >> 1, wn = wid & 1;

  // staging: LDS[r][c] = G[r][c ^ ((r&7)<<4)] via pre-swizzled per-lane global src
  int cswz = (((lane & 7) ^ (lane >> 3)) << 4);                  // bytes
  const char* pa = (const char*)encb + ((size_t)(mtile*128 + wid*8 + (lane>>3)))*2048 + cswz;
  const char* pb = (const char*)uwb  + ((size_t)(ntile*128 + wid*8 + (lane>>3)))*2048 + cswz;

  int aAddr[4], bAddr[4], aXor[4], bXor[4];
  #pragma unroll
  for (int i = 0; i < 4; ++i){
    int ra = wm*64 + i*16 + (lane & 15);
    aAddr[i] = ra * 128; aXor[i] = (ra & 7) << 4;
    int rb = wn*64 + i*16 + (lane & 15);
    bAddr[i] = rb * 128; bXor[i] = (rb & 7) << 4;
  }
  int klane = (lane >> 4) << 4;

  f32x4 acc[4][4] = {};
  char* bA = smem; char* bB = smem + 16384;

  for (int ks = 0; ks < 16; ++ks){
    __syncthreads();                      // previous compute done before overwrite
    #pragma unroll
    for (int i = 0; i < 4; ++i){
      gload_lds16(pa + (size_t)i*65536 + ks*128, bA + (i*4 + wid)*1024);
      gload_lds16(pb + (size_t)i*65536 + ks*128, bB + (i*4 + wid)*1024);
    }
    __syncthreads();                      // vmcnt(0)+lgkmcnt(0) drain -> tile ready
    #pragma unroll
    for (int kk = 0; kk < 2; ++kk){
      short8 af[4], bv[4];
      int kb = kk * 64 + klane;
      #pragma unroll
      for (int i = 0; i < 4; ++i){
        af[i] = *(const short8*)(bA + aAddr[i] + (kb ^ aXor[i]));
        bv[i] = *(const short8*)(bB + bAddr[i] + (kb ^ bXor[i]));
      }
      #pragma unroll
      for (int mi = 0; mi < 4; ++mi)
        #pragma unroll
        for (int ni = 0; ni < 4; ++ni)
          acc[mi][ni] = __builtin_amdgcn_mfma_f32_16x16x32_bf16(af[mi], bv[ni], acc[mi][ni], 0, 0, 0);
    }
  }

  int s_idx = mtile * 2 + wm;            // each wave owns one s (its 64 rows = 64 b)
  if (s_idx < m){
    float ubv[4], vwv[4];
    #pragma unroll
    for (int ni = 0; ni < 4; ++ni){
      int nt = ntile*128 + wn*64 + ni*16 + (lane & 15);
      ubv[ni] = Ub[nt]; vwv[ni] = vw[nt];
    }
    #pragma unroll
    for (int mi = 0; mi < 4; ++mi){
      #pragma unroll
      for (int j = 0; j < 4; ++j){
        int b = mi*16 + ((lane >> 4) << 2) + j;   // C/D: col=lane&15, row=(lane>>4)*4+j
        const float* wqrow = wqm + b * 1024;
        float asum = 0.f;
        #pragma unroll
        for (int ni = 0; ni < 4; ++ni){
          int nt = ntile*128 + wn*64 + ni*16 + (lane & 15);
          float uh = acc[mi][ni][j] + ubv[ni] + wqrow[nt];
          asum += tanh_fast(uh) * vwv[ni];
        }
        asum += __shfl_xor(asum, 1, 64);
        asum += __shfl_xor(asum, 2, 64);
        asum += __shfl_xor(asum, 4, 64);
        asum += __shfl_xor(asum, 8, 64);
        if ((lane & 15) == 0)
          scores_part[(ntile*2 + wn)*65536 + s_idx*64 + b] = asum;
      }
    }
  }
}

// ---------- fallback score GEMM (fp32 inputs, in-kernel cvt) ----------
__global__ __launch_bounds__(256, 2)
void score_gemm_f32(const float* __restrict__ enc, const float* __restrict__ Uw,
                    const float* __restrict__ Ub, const float* __restrict__ vw,
                    const float* __restrict__ wqm, const int* __restrict__ maskp,
                    float* __restrict__ scores_part)
{
  __shared__ char smem[65536];
  int m = *maskp; m = m < 0 ? 0 : (m > SEQ ? SEQ : m);
  int bI = blockIdx.x;
  int mtile = bI & 511, ntile = bI >> 9;
  if (mtile * 2 >= m) return;
  int row0 = mtile * 128;
  int t = threadIdx.x, lane = t & 63;
  int wid = t >> 6, wm = wid >> 1, wn = wid & 1;
  int srow = t >> 2;
  int sk4 = (t & 3) << 4;
  int kb0 = (t & 3) << 5;

  const float* Ag0 = enc + (size_t)(row0 + srow) * 1024 + sk4;
  const float* Ag1 = Ag0 + 64 * 1024;
  const float* Bg0 = Uw  + (size_t)(ntile * 128 + srow) * 1024 + sk4;
  const float* Bg1 = Bg0 + 64 * 1024;

  float4 fa0[4], fa1[4], fb0[4], fb1[4];
  int aAddr[4], bAddr[4], aXor[4], bXor[4];
  #pragma unroll
  for (int i = 0; i < 4; ++i){
    int ra = wm*64 + i*16 + (lane & 15);
    aAddr[i] = ra * 128; aXor[i] = (ra & 7) << 4;
    int rb = wn*64 + i*16 + (lane & 15);
    bAddr[i] = rb * 128; bXor[i] = (rb & 7) << 4;
  }
  int klane = (lane >> 4) << 4;
  f32x4 acc[4][4] = {};

  ld4(fa0, Ag0); ld4(fa1, Ag1); ld4(fb0, Bg0); ld4(fb1, Bg1);
  {
    char* bA = smem; char* bB = smem + 16384;
    cvt_store(bA, srow,      kb0, fa0);
    cvt_store(bA, srow + 64, kb0, fa1);
    cvt_store(bB, srow,      kb0, fb0);
    cvt_store(bB, srow + 64, kb0, fb1);
  }
  #pragma unroll 2
  for (int ks = 0; ks < 16; ++ks){
    int buf = ks & 1;
    if (ks < 15){
      int ko = (ks + 1) * 64;
      ld4(fa0, Ag0 + ko); ld4(fa1, Ag1 + ko);
      ld4(fb0, Bg0 + ko); ld4(fb1, Bg1 + ko);
    }
    __syncthreads();
    {
      char* bA = smem + buf * 32768;
      char* bB = bA + 16384;
      #pragma unroll
      for (int kk = 0; kk < 2; ++kk){
        short8 af[4], bv[4];
        int kb = kk * 64 + klane;
        #pragma unroll
        for (int i = 0; i < 4; ++i){
          af[i] = *(const short8*)(bA + aAddr[i] + (kb ^ aXor[i]));
          bv[i] = *(const short8*)(bB + bAddr[i] + (kb ^ bXor[i]));
        }
        #pragma unroll
        for (int mi = 0; mi < 4; ++mi)
          #pragma unroll
          for (int ni = 0; ni < 4; ++ni)
            acc[mi][ni] = __builtin_amdgcn_mfma_f32_16x16x32_bf16(af[mi], bv[ni], acc[mi][ni], 0, 0, 0);
      }
    }
    if (ks < 15){
      int nb = buf ^ 1;
      char* bA = smem + nb * 32768; char* bB = bA + 16384;
      cvt_store(bA, srow,      kb0, fa0);
      cvt_store(bA, srow + 64, kb0, fa1);
      cvt_store(bB, srow,      kb0, fb0);
      cvt_store(bB, srow + 64, kb0, fb1);
    }
  }

  int s_idx = mtile * 2 + wm;
  if (s_idx < m){
    float ubv[4], vwv[4];
    #pragma unroll
    for (int ni = 0; ni < 4; ++ni){
      int nt = ntile*128 + wn*64 + ni*16 + (lane & 15);
      ubv[ni] = Ub[nt]; vwv[ni] = vw[nt];
    }
    #pragma unroll
    for (int mi = 0; mi < 4; ++mi){
      #pragma unroll
      for (int j = 0; j < 4; ++j){
        int b = mi*16 + ((lane >> 4) << 2) + j;
        const float* wqrow = wqm + b * 1024;
        float asum = 0.f;
        #pragma unroll
        for (int ni = 0; ni < 4; ++ni){
          int nt = ntile*128 + wn*64 + ni*16 + (lane & 15);
          float uh = acc[mi][ni][j] + ubv[ni] + wqrow[nt];
          asum += tanh_fast(uh) * vwv[ni];
        }
        asum += __shfl_xor(asum, 1, 64);
        asum += __shfl_xor(asum, 2, 64);
        asum += __shfl_xor(asum, 4, 64);
        asum += __shfl_xor(asum, 8, 64);
        if ((lane & 15) == 0)
          scores_part[(ntile*2 + wn)*65536 + s_idx*64 + b] = asum;
      }
    }
  }
}

// ---------- small GEMM: C[64,N] = A[64,K] @ B[N,K]^T, bf16 MFMA ----------
// gridDim.z>1: write z-partials to Cpart[z][64][N] (no bias); else direct + bias
__global__ __launch_bounds__(256)
void gemm_m64(const float* __restrict__ A, const float* __restrict__ Bw,
              const float* __restrict__ bias, float* __restrict__ C,
              float* __restrict__ Cpart, int N, int K, int stepsPerZ)
{
  __shared__ unsigned short sA[2][64 * 40];
  __shared__ unsigned short sB[2][128 * 40];
  int t = threadIdx.x, lane = t & 63, wid = t >> 6;
  int ntile = blockIdx.x, z = blockIdx.z;
  int arow = t >> 2, ak = (t & 3) * 8;
  int brow = t >> 1, bk = (t & 1) * 16;
  const float* Ap = A + (size_t)arow * K + ak + (size_t)z * stepsPerZ * 32;
  const float* Bp = Bw + (size_t)(ntile * 128 + brow) * K + bk + (size_t)z * stepsPerZ * 32;
  int klane = (lane >> 4) << 4;
  f32x4 acc[4][2] = {};
  float4 a0, a1, b0, b1, b2, b3;

  {
    const float4* pa = (const float4*)Ap;
    a0 = pa[0]; a1 = pa[1];
    const float4* pb = (const float4*)Bp;
    b0 = pb[0]; b1 = pb[1]; b2 = pb[2]; b3 = pb[3];
    uint4 u;
    u.x = pk2(a0.x,a0.y); u.y = pk2(a0.z,a0.w);
    u.z = pk2(a1.x,a1.y); u.w = pk2(a1.z,a1.w);
    *(uint4*)((char*)sA[0] + arow*80 + ak*2) = u;
    u.x = pk2(b0.x,b0.y); u.y = pk2(b0.z,b0.w);
    u.z = pk2(b1.x,b1.y); u.w = pk2(b1.z,b1.w);
    *(uint4*)((char*)sB[0] + brow*80 + bk*2) = u;
    u.x = pk2(b2.x,b2.y); u.y = pk2(b2.z,b2.w);
    u.z = pk2(b3.x,b3.y); u.w = pk2(b3.z,b3.w);
    *(uint4*)((char*)sB[0] + brow*80 + bk*2 + 16) = u;
  }

  for (int ks = 0; ks < stepsPerZ; ++ks){
    int buf = ks & 1;
    if (ks + 1 < stepsPerZ){
      int kg = (ks + 1) * 32;
      const float4* pa = (const float4*)(Ap + kg);
      a0 = pa[0]; a1 = pa[1];
      const float4* pb = (const float4*)(Bp + kg);
      b0 = pb[0]; b1 = pb[1]; b2 = pb[2]; b3 = pb[3];
    }
    __syncthreads();
    {
      short8 af[4], bv[2];
      #pragma unroll
      for (int mi = 0; mi < 4; ++mi)
        af[mi] = *(const short8*)((char*)sA[buf] + (mi*16 + (lane & 15))*80 + klane);
      #pragma unroll
      for (int ni = 0; ni < 2; ++ni)
        bv[ni] = *(const short8*)((char*)sB[buf] + (wid*32 + ni*16 + (lane & 15))*80 + klane);
      #pragma unroll
      for (int mi = 0; mi < 4; ++mi)
        #pragma unroll
        for (int ni = 0; ni < 2; ++ni)
          acc[mi][ni] = __builtin_amdgcn_mfma_f32_16x16x32_bf16(af[mi], bv[ni], acc[mi][ni], 0, 0, 0);
    }
    if (ks + 1 < stepsPerZ){
      int nb = buf ^ 1;
      uint4 u;
      u.x = pk2(a0.x,a0.y); u.y = pk2(a0.z,a0.w);
      u.z = pk2(a1.x,a1.y); u.w = pk2(a1.z,a1.w);
      *(uint4*)((char*)sA[nb] + arow*80 + ak*2) = u;
      u.x = pk2(b0.x,b0.y); u.y = pk2(b0.z,b0.w);
      u.z = pk2(b1.x,b1.y); u.w = pk2(b1.z,b1.w);
      *(uint4*)((char*)sB[nb] + brow*80 + bk*2) = u;
      u.x = pk2(b2.x,b2.y); u.y = pk2(b2.z,b2.w);
      u.z = pk2(b3.x,b3.y); u.w = pk2(b3.z,b3.w);
      *(uint4*)((char*)sB[nb] + brow*80 + bk*2 + 16) = u;
    }
  }

  bool multi = (gridDim.z > 1);
  #pragma unroll
  for (int ni = 0; ni < 2; ++ni){
    int cg = ntile*128 + wid*32 + ni*16 + (lane & 15);
    float bz = (bias && !multi) ? bias[cg] : 0.f;
    #pragma unroll
    for (int mi = 0; mi < 4; ++mi){
      int r0 = mi*16 + ((lane >> 4) << 2);
      #pragma unroll
      for (int j = 0; j < 4; ++j){
        float val = acc[mi][ni][j] + bz;
        if (multi) Cpart[((size_t)z*64 + r0 + j)*N + cg] = val;
        else       C[(size_t)(r0 + j)*N + cg] = val;
      }
    }
  }
}

// ---------- reduce 8 z-partials + bias ----------
__global__ __launch_bounds__(256)
void reduce8_bias(const float* __restrict__ part, const float* __restrict__ bias,
                  float* __restrict__ out, int N)
{
  int idx = blockIdx.x*256 + threadIdx.x;       // one f32x4 per thread
  int r = idx / (N >> 2), c4 = (idx % (N >> 2)) * 4;
  f32x4 acc = *(const f32x4*)(bias + c4);
  #pragma unroll
  for (int z = 0; z < 8; ++z)
    acc += *(const f32x4*)(part + ((size_t)z*64 + r)*N + c4);
  *(f32x4*)(out + (size_t)r*N + c4) = acc;
}

// ---------- softmax over S (sums 16 score partials) ----------
__global__ __launch_bounds__(256)
void softmax_attn(const float* __restrict__ sp, const float* __restrict__ vb,
                  const int* __restrict__ maskp, float* __restrict__ attn)
{
  __shared__ float sb[4];
  int b = blockIdx.x, t = threadIdx.x, lane = t & 63, wid = t >> 6;
  int m = *maskp; m = m < 0 ? 0 : (m > SEQ ? SEQ : m);
  float vb0 = vb[0];
  float v[4]; float mx = -1e30f;
  #pragma unroll
  for (int k = 0; k < 4; ++k){
    int s = t + k * 256;
    float x = 0.f;
    if (s < m){
      float a = 0.f;
      #pragma unroll
      for (int p = 0; p < 16; ++p) a += sp[p*65536 + s*64 + b];
      x = a + vb0;
    }
    v[k] = x; mx = fmaxf(mx, x);
  }
  for (int d = 1; d < 64; d <<= 1) mx = fmaxf(mx, __shfl_xor(mx, d, 64));
  if (lane == 0) sb[wid] = mx;
  __syncthreads();
  mx = fmaxf(fmaxf(sb[0], sb[1]), fmaxf(sb[2], sb[3]));
  float sum = 0.f;
  #pragma unroll
  for (int k = 0; k < 4; ++k){ v[k] = expf(v[k] - mx); sum += v[k]; }
  for (int d = 1; d < 64; d <<= 1) sum += __shfl_xor(sum, d, 64);
  __syncthreads();
  if (lane == 0) sb[wid] = sum;
  __syncthreads();
  sum = sb[0] + sb[1] + sb[2] + sb[3];
  #pragma unroll
  for (int k = 0; k < 4; ++k) attn[b*1024 + t + k*256] = v[k] / sum;
}

// ---------- ctx partials (bf16 enc) ----------
__global__ __launch_bounds__(256)
void ctx_bf16(const float* __restrict__ attn, const unsigned short* __restrict__ encb,
              float* __restrict__ ctx_part)
{
  int b = blockIdx.x >> 4, ch = blockIdx.x & 15;
  int t = threadIdx.x;
  __shared__ float a_s[64];
  if (t < 64) a_s[t] = attn[b*1024 + ch*64 + t];
  __syncthreads();
  const unsigned short* base = encb + ((size_t)(ch*64)*64 + b)*1024 + t*4;
  f32x4 acc = {};
  for (int s2 = 0; s2 < 64; ++s2){
    ushort4 vv = *(const ushort4*)(base + (size_t)s2*65536);
    float w = a_s[s2];
    acc.x += w * bf2f(vv.x); acc.y += w * bf2f(vv.y);
    acc.z += w * bf2f(vv.z); acc.w += w * bf2f(vv.w);
  }
  *(f32x4*)(ctx_part + (size_t)(b*16 + ch)*1024 + t*4) = acc;
}

// ---------- ctx partials (fp32 enc, fallback) ----------
__global__ __launch_bounds__(256)
void ctx_f32(const float* __restrict__ attn, const float* __restrict__ enc,
             float* __restrict__ ctx_part)
{
  int b = blockIdx.x >> 4, ch = blockIdx.x & 15;
  int t = threadIdx.x;
  __shared__ float a_s[64];
  if (t < 64) a_s[t] = attn[b*1024 + ch*64 + t];
  __syncthreads();
  const float* ep = enc + (size_t)(ch * 64) * 65536 + b * 1024 + t * 4;
  f32x4 acc = {};
  for (int s2 = 0; s2 < 64; ++s2){
    f32x4 v = *(const f32x4*)(ep + (size_t)s2 * 65536);
    acc += a_s[s2] * v;
  }
  *(f32x4*)(ctx_part + (size_t)(b*16 + ch)*1024 + t*4) = acc;
}

// ---------- build xcat = [prev_y | sum ctx_part] ----------
__global__ __launch_bounds__(256)
void build_xcat(const float* __restrict__ part, const float* __restrict__ py,
                float* __restrict__ xcat)
{
  int b = blockIdx.x, t = threadIdx.x;
  f32x4 acc = {};
  #pragma unroll
  for (int c2 = 0; c2 < 16; ++c2)
    acc += *(const f32x4*)(part + (size_t)(b*16 + c2) * 1024 + t * 4);
  *(f32x4*)(xcat + b*1536 + 512 + t*4) = acc;
  if (t < 128)
    *(f32x4*)(xcat + b*1536 + t*4) = *(const f32x4*)(py + b*512 + t*4);
}

// ---------- fused: reduce gi/gh partials + biases + GRU ----------
__global__ __launch_bounds__(256)
void gru_fused(const float* __restrict__ gip, const float* __restrict__ ghp,
               const float* __restrict__ b_ih, const float* __restrict__ b_hh,
               const float* __restrict__ h, float* __restrict__ hnew)
{
  int idx = blockIdx.x * 256 + threadIdx.x;
  int b = idx >> 10, i = idx & 1023;
  float gr = b_ih[i], gz = b_ih[1024+i], gn = b_ih[2048+i];
  float hr = b_hh[i], hz = b_hh[1024+i], hn = b_hh[2048+i];
  #pragma unroll
  for (int z = 0; z < 8; ++z){
    const float* p = gip + (size_t)z*196608 + b*3072;
    gr += p[i]; gz += p[1024+i]; gn += p[2048+i];
    const float* q = ghp + (size_t)z*196608 + b*3072;
    hr += q[i]; hz += q[1024+i]; hn += q[2048+i];
  }
  float r  = sigm(gr + hr);
  float zz = sigm(gz + hz);
  float n  = tanhf(gn + r * hn);
  hnew[idx] = (1.f - zz) * n + zz * h[idx];
}

// ---------- log_softmax in-place over V ----------
__global__ __launch_bounds__(1024)
void logsoftmax_kernel(float* __restrict__ logits)
{
  __shared__ float sb[16];
  int b = blockIdx.x, t = threadIdx.x, lane = t & 63, wid = t >> 6;
  float* row = logits + (size_t)b * VOCAB;
  float v[32]; float mx = -1e30f;
  #pragma unroll
  for (int k = 0; k < 32; ++k){
    int idx = t + k * 1024;
    if (idx < VOCAB){ v[k] = row[idx]; mx = fmaxf(mx, v[k]); }
    else v[k] = -1e30f;
  }
  for (int d = 1; d < 64; d <<= 1) mx = fmaxf(mx, __shfl_xor(mx, d, 64));
  if (lane == 0) sb[wid] = mx;
  __syncthreads();
  float m2 = -1e30f;
  for (int i = 0; i < 16; ++i) m2 = fmaxf(m2, sb[i]);
  mx = m2;
  float sum = 0.f;
  #pragma unroll
  for (int k = 0; k < 32; ++k){
    int idx = t + k * 1024;
    if (idx < VOCAB) sum += expf(v[k] - mx);
  }
  for (int d = 1; d < 64; d <<= 1) sum += __shfl_xor(sum, d, 64);
  __syncthreads();
  if (lane == 0) sb[wid] = sum;
  __syncthreads();
  float s2 = 0.f;
  for (int i = 0; i < 16; ++i) s2 += sb[i];
  float lse = mx + logf(s2);
  #pragma unroll
  for (int k = 0; k < 32; ++k){
    int idx = t + k * 1024;
    if (idx < VOCAB) row[idx] = v[k] - lse;
  }
}

// ---------- launcher ----------
extern "C" void kernel_launch(void* const* d_in, const int* in_sizes, int n_in,
                              void* d_out, int out_size, void* d_ws, size_t ws_size,
                              hipStream_t stream)
{
  const float* prev_y = (const float*)d_in[0];
  const float* prev_h = (const float*)d_in[1];
  const float* enc    = (const float*)d_in[2];
  const float* U_w    = (const float*)d_in[3];
  const float* U_b    = (const float*)d_in[4];
  const float* W_w    = (const float*)d_in[5];
  const float* W_b    = (const float*)d_in[6];
  const float* v_w    = (const float*)d_in[7];
  const float* v_b    = (const float*)d_in[8];
  const float* Wc_w   = (const float*)d_in[9];
  const float* Wc_b   = (const float*)d_in[10];
  const float* W_ih   = (const float*)d_in[11];
  const float* W_hh   = (const float*)d_in[12];
  const float* b_ih   = (const float*)d_in[13];
  const float* b_hh   = (const float*)d_in[14];
  const float* Wout_w = (const float*)d_in[15];
  const float* Wout_b = (const float*)d_in[16];
  const int*   maskp  = (const int*)d_in[17];

  char* wsb = (char*)d_ws;
  const size_t ENC_B = 134217728ULL;   // 64M bf16
  const size_t UW_B  = 2097152ULL;     // 1M bf16
  const size_t FLOATS_B = 26083328ULL; // float region below
  bool big = ws_size >= ENC_B + UW_B + FLOATS_B;

  unsigned short* encb = (unsigned short*)wsb;
  unsigned short* uwb  = (unsigned short*)(wsb + ENC_B);
  float* f = (float*)(wsb + (big ? (ENC_B + UW_B) : 0));
  float* scores_part = f;                       // 16*1024*64 = 1048576
  float* wq_part     = scores_part + 1048576;   // 8*64*1024  = 524288
  float* wq          = wq_part + 524288;        // 65536
  float* ctx_part    = wq + 65536;              // 16*64*1024 = 1048576
  float* xcat        = ctx_part + 1048576;      // 98304
  float* xvec_part   = xcat + 98304;            // 524288
  float* xvec        = xvec_part + 524288;      // 65536
  float* gi_part     = xvec + 65536;            // 8*64*3072 = 1572864
  float* gh_part     = gi_part + 1572864;       // 1572864

  float* out_logp = (float*)d_out;
  float* out_h    = out_logp + 64 * VOCAB;
  float* out_attn = out_h + 65536;

  if (big)
    convert_all<<<2048, 256, 0, stream>>>(U_w, enc, uwb, encb);

  // wq = prev_h @ W_w^T + W_b  (z-split partials + reduce)
  gemm_m64<<<dim3(8,1,8), 256, 0, stream>>>(prev_h, W_w, nullptr, nullptr, wq_part, 1024, 1024, 4);
  reduce8_bias<<<64, 256, 0, stream>>>(wq_part, W_b, wq, 1024);

  if (big)
    score_gemm_bf16<<<4096, 256, 0, stream>>>(encb, uwb, U_b, v_w, wq, maskp, scores_part);
  else
    score_gemm_f32<<<4096, 256, 0, stream>>>(enc, U_w, U_b, v_w, wq, maskp, scores_part);

  softmax_attn<<<64, 256, 0, stream>>>(scores_part, v_b, maskp, out_attn);

  if (big) ctx_bf16<<<1024, 256, 0, stream>>>(out_attn, encb, ctx_part);
  else     ctx_f32<<<1024, 256, 0, stream>>>(out_attn, enc, ctx_part);
  build_xcat<<<64, 256, 0, stream>>>(ctx_part, prev_y, xcat);

  gemm_m64<<<dim3(8,1,8), 256, 0, stream>>>(xcat, Wc_w, nullptr, nullptr, xvec_part, 1024, 1536, 6);
  reduce8_bias<<<64, 256, 0, stream>>>(xvec_part, Wc_b, xvec, 1024);

  gemm_m64<<<dim3(24,1,8), 256, 0, stream>>>(xvec, W_ih, nullptr, nullptr, gi_part, 3072, 1024, 4);
  gemm_m64<<<dim3(24,1,8), 256, 0, stream>>>(prev_h, W_hh, nullptr, nullptr, gh_part, 3072, 1024, 4);
  gru_fused<<<256, 256, 0, stream>>>(gi_part, gh_part, b_ih, b_hh, prev_h, out_h);

  gemm_m64<<<dim3(250,1,1), 256, 0, stream>>>(out_h, Wout_w, Wout_b, out_logp, nullptr, VOCAB, 1024, 32);
  logsoftmax_kernel<<<64, 1024, 0, stream>>>(out_logp);
}

// Round 7
// 763.567 us; speedup vs baseline: 1.0830x; 1.0560x over previous
//
#include <hip/hip_runtime.h>

typedef float f32x4 __attribute__((ext_vector_type(4)));
typedef short short8 __attribute__((ext_vector_type(8)));
typedef unsigned int u32;

#define SEQ   1024
#define VOCAB 32000

// ---------- helpers ----------
__device__ __forceinline__ unsigned short f2bf(float f){
  union { float f; unsigned u; } v; v.f = f;
  unsigned r = v.u + 0x7FFFu + ((v.u >> 16) & 1u);   // RNE
  return (unsigned short)(r >> 16);
}
__device__ __forceinline__ unsigned pk2(float a, float b){
  return (unsigned)f2bf(a) | ((unsigned)f2bf(b) << 16);
}
__device__ __forceinline__ float bf2f(unsigned short h){
  union { unsigned u; float f; } v; v.u = ((unsigned)h) << 16; return v.f;
}
__device__ __forceinline__ float tanh_fast(float x){
  float a = fminf(fmaxf(x, -15.f), 15.f);
  float e = __expf(2.f * a);
  return (e - 1.f) / (e + 1.f);
}
__device__ __forceinline__ float sigm(float x){ return 1.f / (1.f + expf(-x)); }

__device__ __forceinline__ void ld4(float4* dst, const float* p){
  const float4* q = (const float4*)p;
  dst[0]=q[0]; dst[1]=q[1]; dst[2]=q[2]; dst[3]=q[3];
}
__device__ __forceinline__ void cvt_store(char* base, int row, int kb0, const float4* f){
  int xs = (row & 7) << 4;
  uint4 u;
  u.x = pk2(f[0].x, f[0].y); u.y = pk2(f[0].z, f[0].w);
  u.z = pk2(f[1].x, f[1].y); u.w = pk2(f[1].z, f[1].w);
  *(uint4*)(base + row*128 + (kb0 ^ xs)) = u;
  u.x = pk2(f[2].x, f[2].y); u.y = pk2(f[2].z, f[2].w);
  u.z = pk2(f[3].x, f[3].y); u.w = pk2(f[3].z, f[3].w);
  *(uint4*)(base + row*128 + ((kb0 + 16) ^ xs)) = u;
}
// async global(16B) -> LDS, wave-uniform LDS base + lane*16
__device__ __forceinline__ void gload_lds16(const void* g, void* l){
  __builtin_amdgcn_global_load_lds((const __attribute__((address_space(1))) u32*)g,
                                   (__attribute__((address_space(3))) u32*)l, 16, 0, 0);
}

// ---------- convert U_w (1M) + enc (64M) fp32 -> bf16 ----------
__global__ __launch_bounds__(256)
void convert_all(const float* __restrict__ uw, const float* __restrict__ enc,
                 unsigned short* __restrict__ uwb, unsigned short* __restrict__ encb)
{
  const int UWC = 131072;                 // 1M/8 chunks
  const int TOT = UWC + 8388608;          // + 64M/8 chunks
  int stride = gridDim.x * 256;
  for (int c = blockIdx.x*256 + threadIdx.x; c < TOT; c += stride){
    const float* src; unsigned short* dst;
    if (c < UWC){ src = uw + (size_t)c*8;        dst = uwb + (size_t)c*8; }
    else        { size_t e = (size_t)(c-UWC)*8;  src = enc + e; dst = encb + e; }
    float4 f0 = ((const float4*)src)[0], f1 = ((const float4*)src)[1];
    uint4 u;
    u.x = pk2(f0.x,f0.y); u.y = pk2(f0.z,f0.w);
    u.z = pk2(f1.x,f1.y); u.w = pk2(f1.z,f1.w);
    *(uint4*)dst = u;
  }
}

// ---------- fused score GEMM (bf16, dbuf LDS + counted vmcnt pipeline) ----------
// scores_part[nt*2+wn][b][s] = partial of v·tanh(uh + Ub + wq) over this block's 64 A-cols
__global__ __launch_bounds__(256)
void score_gemm_bf16(const unsigned short* __restrict__ encb,
                     const unsigned short* __restrict__ uwb,
                     const float* __restrict__ Ub, const float* __restrict__ vw,
                     const float* __restrict__ wqm, const int* __restrict__ maskp,
                     float* __restrict__ scores_part)
{
  __shared__ char smem[65536];           // 2 bufs x (A 16KB + B 16KB)
  int m = *maskp; m = m < 0 ? 0 : (m > SEQ ? SEQ : m);
  int bI = blockIdx.x;
  int mtile = bI & 511, ntile = bI >> 9; // same mtile -> same XCD (stride 512 ≡ 0 mod 8)
  if (mtile * 2 >= m) return;
  int t = threadIdx.x, lane = t & 63, wid = t >> 6;
  int wm = wid >> 1, wn = wid & 1;

  // staging: LDS[r][c] = G[r][c ^ ((r&7)<<4)] via pre-swizzled per-lane global src
  int cswz = (((lane & 7) ^ (lane >> 3)) << 4);                  // bytes
  const char* pa = (const char*)encb + ((size_t)(mtile*128 + wid*8 + (lane>>3)))*2048 + cswz;
  const char* pb = (const char*)uwb  + ((size_t)(ntile*128 + wid*8 + (lane>>3)))*2048 + cswz;

  int aAddr[4], bAddr[4], aXor[4], bXor[4];
  #pragma unroll
  for (int i = 0; i < 4; ++i){
    int ra = wm*64 + i*16 + (lane & 15);
    aAddr[i] = ra * 128; aXor[i] = (ra & 7) << 4;
    int rb = wn*64 + i*16 + (lane & 15);
    bAddr[i] = rb * 128; bXor[i] = (rb & 7) << 4;
  }
  int klane = (lane >> 4) << 4;
  int ldsDst = wid * 1024;               // wave-uniform LDS offset base

  f32x4 acc[4][4] = {};

  // prologue: issue tile 0 into buf0 (8 async loads in flight)
  {
    char* bA = smem; char* bB = smem + 16384;
    #pragma unroll
    for (int i = 0; i < 4; ++i){
      gload_lds16(pa + (size_t)i*65536, bA + i*4096 + ldsDst);
      gload_lds16(pb + (size_t)i*65536, bB + i*4096 + ldsDst);
    }
  }

  for (int ks = 0; ks < 16; ++ks){
    if (ks < 15){
      // issue tile ks+1 into the other buffer, then wait for tile ks (8 oldest)
      char* bA = smem + ((ks+1)&1)*32768; char* bB = bA + 16384;
      #pragma unroll
      for (int i = 0; i < 4; ++i){
        gload_lds16(pa + (size_t)i*65536 + (ks+1)*128, bA + i*4096 + ldsDst);
        gload_lds16(pb + (size_t)i*65536 + (ks+1)*128, bB + i*4096 + ldsDst);
      }
      asm volatile("s_waitcnt vmcnt(8)" ::: "memory");
    } else {
      asm volatile("s_waitcnt vmcnt(0)" ::: "memory");
    }
    __builtin_amdgcn_s_barrier();        // all waves' tile-ks DMA landed
    {
      char* bA = smem + (ks&1)*32768; char* bB = bA + 16384;
      #pragma unroll
      for (int kk = 0; kk < 2; ++kk){
        short8 af[4], bv[4];
        int kb = kk * 64 + klane;
        #pragma unroll
        for (int i = 0; i < 4; ++i){
          af[i] = *(const short8*)(bA + aAddr[i] + (kb ^ aXor[i]));
          bv[i] = *(const short8*)(bB + bAddr[i] + (kb ^ bXor[i]));
        }
        #pragma unroll
        for (int mi = 0; mi < 4; ++mi)
          #pragma unroll
          for (int ni = 0; ni < 4; ++ni)
            acc[mi][ni] = __builtin_amdgcn_mfma_f32_16x16x32_bf16(af[mi], bv[ni], acc[mi][ni], 0, 0, 0);
      }
    }
    __builtin_amdgcn_s_barrier();        // compute(buf ks) done before it is overwritten
  }

  int s_idx = mtile * 2 + wm;            // each wave owns one s (its 64 rows = 64 b)
  if (s_idx < m){
    float ubv[4], vwv[4];
    #pragma unroll
    for (int ni = 0; ni < 4; ++ni){
      int nt = ntile*128 + wn*64 + ni*16 + (lane & 15);
      ubv[ni] = Ub[nt]; vwv[ni] = vw[nt];
    }
    #pragma unroll
    for (int mi = 0; mi < 4; ++mi){
      #pragma unroll
      for (int j = 0; j < 4; ++j){
        int b = mi*16 + ((lane >> 4) << 2) + j;   // C/D: col=lane&15, row=(lane>>4)*4+j
        const float* wqrow = wqm + b * 1024;
        float asum = 0.f;
        #pragma unroll
        for (int ni = 0; ni < 4; ++ni){
          int nt = ntile*128 + wn*64 + ni*16 + (lane & 15);
          float uh = acc[mi][ni][j] + ubv[ni] + wqrow[nt];
          asum += tanh_fast(uh) * vwv[ni];
        }
        asum += __shfl_xor(asum, 1, 64);
        asum += __shfl_xor(asum, 2, 64);
        asum += __shfl_xor(asum, 4, 64);
        asum += __shfl_xor(asum, 8, 64);
        if ((lane & 15) == 0)
          scores_part[(ntile*2 + wn)*65536 + b*1024 + s_idx] = asum;   // [plane][b][s]
      }
    }
  }
}

// ---------- fallback score GEMM (fp32 inputs, in-kernel cvt) ----------
__global__ __launch_bounds__(256, 2)
void score_gemm_f32(const float* __restrict__ enc, const float* __restrict__ Uw,
                    const float* __restrict__ Ub, const float* __restrict__ vw,
                    const float* __restrict__ wqm, const int* __restrict__ maskp,
                    float* __restrict__ scores_part)
{
  __shared__ char smem[65536];
  int m = *maskp; m = m < 0 ? 0 : (m > SEQ ? SEQ : m);
  int bI = blockIdx.x;
  int mtile = bI & 511, ntile = bI >> 9;
  if (mtile * 2 >= m) return;
  int row0 = mtile * 128;
  int t = threadIdx.x, lane = t & 63;
  int wid = t >> 6, wm = wid >> 1, wn = wid & 1;
  int srow = t >> 2;
  int sk4 = (t & 3) << 4;
  int kb0 = (t & 3) << 5;

  const float* Ag0 = enc + (size_t)(row0 + srow) * 1024 + sk4;
  const float* Ag1 = Ag0 + 64 * 1024;
  const float* Bg0 = Uw  + (size_t)(ntile * 128 + srow) * 1024 + sk4;
  const float* Bg1 = Bg0 + 64 * 1024;

  float4 fa0[4], fa1[4], fb0[4], fb1[4];
  int aAddr[4], bAddr[4], aXor[4], bXor[4];
  #pragma unroll
  for (int i = 0; i < 4; ++i){
    int ra = wm*64 + i*16 + (lane & 15);
    aAddr[i] = ra * 128; aXor[i] = (ra & 7) << 4;
    int rb = wn*64 + i*16 + (lane & 15);
    bAddr[i] = rb * 128; bXor[i] = (rb & 7) << 4;
  }
  int klane = (lane >> 4) << 4;
  f32x4 acc[4][4] = {};

  ld4(fa0, Ag0); ld4(fa1, Ag1); ld4(fb0, Bg0); ld4(fb1, Bg1);
  {
    char* bA = smem; char* bB = smem + 16384;
    cvt_store(bA, srow,      kb0, fa0);
    cvt_store(bA, srow + 64, kb0, fa1);
    cvt_store(bB, srow,      kb0, fb0);
    cvt_store(bB, srow + 64, kb0, fb1);
  }
  #pragma unroll 2
  for (int ks = 0; ks < 16; ++ks){
    int buf = ks & 1;
    if (ks < 15){
      int ko = (ks + 1) * 64;
      ld4(fa0, Ag0 + ko); ld4(fa1, Ag1 + ko);
      ld4(fb0, Bg0 + ko); ld4(fb1, Bg1 + ko);
    }
    __syncthreads();
    {
      char* bA = smem + buf * 32768;
      char* bB = bA + 16384;
      #pragma unroll
      for (int kk = 0; kk < 2; ++kk){
        short8 af[4], bv[4];
        int kb = kk * 64 + klane;
        #pragma unroll
        for (int i = 0; i < 4; ++i){
          af[i] = *(const short8*)(bA + aAddr[i] + (kb ^ aXor[i]));
          bv[i] = *(const short8*)(bB + bAddr[i] + (kb ^ bXor[i]));
        }
        #pragma unroll
        for (int mi = 0; mi < 4; ++mi)
          #pragma unroll
          for (int ni = 0; ni < 4; ++ni)
            acc[mi][ni] = __builtin_amdgcn_mfma_f32_16x16x32_bf16(af[mi], bv[ni], acc[mi][ni], 0, 0, 0);
      }
    }
    if (ks < 15){
      int nb = buf ^ 1;
      char* bA = smem + nb * 32768; char* bB = bA + 16384;
      cvt_store(bA, srow,      kb0, fa0);
      cvt_store(bA, srow + 64, kb0, fa1);
      cvt_store(bB, srow,      kb0, fb0);
      cvt_store(bB, srow + 64, kb0, fb1);
    }
  }

  int s_idx = mtile * 2 + wm;
  if (s_idx < m){
    float ubv[4], vwv[4];
    #pragma unroll
    for (int ni = 0; ni < 4; ++ni){
      int nt = ntile*128 + wn*64 + ni*16 + (lane & 15);
      ubv[ni] = Ub[nt]; vwv[ni] = vw[nt];
    }
    #pragma unroll
    for (int mi = 0; mi < 4; ++mi){
      #pragma unroll
      for (int j = 0; j < 4; ++j){
        int b = mi*16 + ((lane >> 4) << 2) + j;
        const float* wqrow = wqm + b * 1024;
        float asum = 0.f;
        #pragma unroll
        for (int ni = 0; ni < 4; ++ni){
          int nt = ntile*128 + wn*64 + ni*16 + (lane & 15);
          float uh = acc[mi][ni][j] + ubv[ni] + wqrow[nt];
          asum += tanh_fast(uh) * vwv[ni];
        }
        asum += __shfl_xor(asum, 1, 64);
        asum += __shfl_xor(asum, 2, 64);
        asum += __shfl_xor(asum, 4, 64);
        asum += __shfl_xor(asum, 8, 64);
        if ((lane & 15) == 0)
          scores_part[(ntile*2 + wn)*65536 + b*1024 + s_idx] = asum;   // [plane][b][s]
      }
    }
  }
}

// ---------- small GEMM: C[64,N] = A[64,K] @ B[N,K]^T, bf16 MFMA ----------
// gridDim.z>1: write z-partials to Cpart[z][64][N] (no bias); else direct + bias
__global__ __launch_bounds__(256)
void gemm_m64(const float* __restrict__ A, const float* __restrict__ Bw,
              const float* __restrict__ bias, float* __restrict__ C,
              float* __restrict__ Cpart, int N, int K, int stepsPerZ)
{
  __shared__ unsigned short sA[2][64 * 40];
  __shared__ unsigned short sB[2][128 * 40];
  int t = threadIdx.x, lane = t & 63, wid = t >> 6;
  int ntile = blockIdx.x, z = blockIdx.z;
  int arow = t >> 2, ak = (t & 3) * 8;
  int brow = t >> 1, bk = (t & 1) * 16;
  const float* Ap = A + (size_t)arow * K + ak + (size_t)z * stepsPerZ * 32;
  const float* Bp = Bw + (size_t)(ntile * 128 + brow) * K + bk + (size_t)z * stepsPerZ * 32;
  int klane = (lane >> 4) << 4;
  f32x4 acc[4][2] = {};
  float4 a0, a1, b0, b1, b2, b3;

  {
    const float4* pa = (const float4*)Ap;
    a0 = pa[0]; a1 = pa[1];
    const float4* pb = (const float4*)Bp;
    b0 = pb[0]; b1 = pb[1]; b2 = pb[2]; b3 = pb[3];
    uint4 u;
    u.x = pk2(a0.x,a0.y); u.y = pk2(a0.z,a0.w);
    u.z = pk2(a1.x,a1.y); u.w = pk2(a1.z,a1.w);
    *(uint4*)((char*)sA[0] + arow*80 + ak*2) = u;
    u.x = pk2(b0.x,b0.y); u.y = pk2(b0.z,b0.w);
    u.z = pk2(b1.x,b1.y); u.w = pk2(b1.z,b1.w);
    *(uint4*)((char*)sB[0] + brow*80 + bk*2) = u;
    u.x = pk2(b2.x,b2.y); u.y = pk2(b2.z,b2.w);
    u.z = pk2(b3.x,b3.y); u.w = pk2(b3.z,b3.w);
    *(uint4*)((char*)sB[0] + brow*80 + bk*2 + 16) = u;
  }

  for (int ks = 0; ks < stepsPerZ; ++ks){
    int buf = ks & 1;
    if (ks + 1 < stepsPerZ){
      int kg = (ks + 1) * 32;
      const float4* pa = (const float4*)(Ap + kg);
      a0 = pa[0]; a1 = pa[1];
      const float4* pb = (const float4*)(Bp + kg);
      b0 = pb[0]; b1 = pb[1]; b2 = pb[2]; b3 = pb[3];
    }
    __syncthreads();
    {
      short8 af[4], bv[2];
      #pragma unroll
      for (int mi = 0; mi < 4; ++mi)
        af[mi] = *(const short8*)((char*)sA[buf] + (mi*16 + (lane & 15))*80 + klane);
      #pragma unroll
      for (int ni = 0; ni < 2; ++ni)
        bv[ni] = *(const short8*)((char*)sB[buf] + (wid*32 + ni*16 + (lane & 15))*80 + klane);
      #pragma unroll
      for (int mi = 0; mi < 4; ++mi)
        #pragma unroll
        for (int ni = 0; ni < 2; ++ni)
          acc[mi][ni] = __builtin_amdgcn_mfma_f32_16x16x32_bf16(af[mi], bv[ni], acc[mi][ni], 0, 0, 0);
    }
    if (ks + 1 < stepsPerZ){
      int nb = buf ^ 1;
      uint4 u;
      u.x = pk2(a0.x,a0.y); u.y = pk2(a0.z,a0.w);
      u.z = pk2(a1.x,a1.y); u.w = pk2(a1.z,a1.w);
      *(uint4*)((char*)sA[nb] + arow*80 + ak*2) = u;
      u.x = pk2(b0.x,b0.y); u.y = pk2(b0.z,b0.w);
      u.z = pk2(b1.x,b1.y); u.w = pk2(b1.z,b1.w);
      *(uint4*)((char*)sB[nb] + brow*80 + bk*2) = u;
      u.x = pk2(b2.x,b2.y); u.y = pk2(b2.z,b2.w);
      u.z = pk2(b3.x,b3.y); u.w = pk2(b3.z,b3.w);
      *(uint4*)((char*)sB[nb] + brow*80 + bk*2 + 16) = u;
    }
  }

  bool multi = (gridDim.z > 1);
  #pragma unroll
  for (int ni = 0; ni < 2; ++ni){
    int cg = ntile*128 + wid*32 + ni*16 + (lane & 15);
    float bz = (bias && !multi) ? bias[cg] : 0.f;
    #pragma unroll
    for (int mi = 0; mi < 4; ++mi){
      int r0 = mi*16 + ((lane >> 4) << 2);
      #pragma unroll
      for (int j = 0; j < 4; ++j){
        float val = acc[mi][ni][j] + bz;
        if (multi) Cpart[((size_t)z*64 + r0 + j)*N + cg] = val;
        else       C[(size_t)(r0 + j)*N + cg] = val;
      }
    }
  }
}

// ---------- reduce 8 z-partials + bias ----------
__global__ __launch_bounds__(256)
void reduce8_bias(const float* __restrict__ part, const float* __restrict__ bias,
                  float* __restrict__ out, int N)
{
  int idx = blockIdx.x*256 + threadIdx.x;       // one f32x4 per thread
  int r = idx / (N >> 2), c4 = (idx % (N >> 2)) * 4;
  f32x4 acc = *(const f32x4*)(bias + c4);
  #pragma unroll
  for (int z = 0; z < 8; ++z)
    acc += *(const f32x4*)(part + ((size_t)z*64 + r)*N + c4);
  *(f32x4*)(out + (size_t)r*N + c4) = acc;
}

// ---------- softmax over S (sums 16 score partials, [plane][b][s] layout) ----------
__global__ __launch_bounds__(256)
void softmax_attn(const float* __restrict__ sp, const float* __restrict__ vb,
                  const int* __restrict__ maskp, float* __restrict__ attn)
{
  __shared__ float sb[4];
  int b = blockIdx.x, t = threadIdx.x, lane = t & 63, wid = t >> 6;
  int m = *maskp; m = m < 0 ? 0 : (m > SEQ ? SEQ : m);
  float vb0 = vb[0];
  float v[4]; float mx = -1e30f;
  #pragma unroll
  for (int k = 0; k < 4; ++k){
    int s = t + k * 256;
    float x = 0.f;
    if (s < m){
      float a = 0.f;
      #pragma unroll
      for (int p = 0; p < 16; ++p) a += sp[p*65536 + b*1024 + s];
      x = a + vb0;
    }
    v[k] = x; mx = fmaxf(mx, x);
  }
  for (int d = 1; d < 64; d <<= 1) mx = fmaxf(mx, __shfl_xor(mx, d, 64));
  if (lane == 0) sb[wid] = mx;
  __syncthreads();
  mx = fmaxf(fmaxf(sb[0], sb[1]), fmaxf(sb[2], sb[3]));
  float sum = 0.f;
  #pragma unroll
  for (int k = 0; k < 4; ++k){ v[k] = expf(v[k] - mx); sum += v[k]; }
  for (int d = 1; d < 64; d <<= 1) sum += __shfl_xor(sum, d, 64);
  __syncthreads();
  if (lane == 0) sb[wid] = sum;
  __syncthreads();
  sum = sb[0] + sb[1] + sb[2] + sb[3];
  #pragma unroll
  for (int k = 0; k < 4; ++k) attn[b*1024 + t + k*256] = v[k] / sum;
}

// ---------- ctx partials (bf16 enc) ----------
__global__ __launch_bounds__(256)
void ctx_bf16(const float* __restrict__ attn, const unsigned short* __restrict__ encb,
              float* __restrict__ ctx_part)
{
  int b = blockIdx.x >> 4, ch = blockIdx.x & 15;
  int t = threadIdx.x;
  __shared__ float a_s[64];
  if (t < 64) a_s[t] = attn[b*1024 + ch*64 + t];
  __syncthreads();
  const unsigned short* base = encb + ((size_t)(ch*64)*64 + b)*1024 + t*4;
  f32x4 acc = {};
  for (int s2 = 0; s2 < 64; ++s2){
    ushort4 vv = *(const ushort4*)(base + (size_t)s2*65536);
    float w = a_s[s2];
    acc.x += w * bf2f(vv.x); acc.y += w * bf2f(vv.y);
    acc.z += w * bf2f(vv.z); acc.w += w * bf2f(vv.w);
  }
  *(f32x4*)(ctx_part + (size_t)(b*16 + ch)*1024 + t*4) = acc;
}

// ---------- ctx partials (fp32 enc, fallback) ----------
__global__ __launch_bounds__(256)
void ctx_f32(const float* __restrict__ attn, const float* __restrict__ enc,
             float* __restrict__ ctx_part)
{
  int b = blockIdx.x >> 4, ch = blockIdx.x & 15;
  int t = threadIdx.x;
  __shared__ float a_s[64];
  if (t < 64) a_s[t] = attn[b*1024 + ch*64 + t];
  __syncthreads();
  const float* ep = enc + (size_t)(ch * 64) * 65536 + b * 1024 + t * 4;
  f32x4 acc = {};
  for (int s2 = 0; s2 < 64; ++s2){
    f32x4 v = *(const f32x4*)(ep + (size_t)s2 * 65536);
    acc += a_s[s2] * v;
  }
  *(f32x4*)(ctx_part + (size_t)(b*16 + ch)*1024 + t*4) = acc;
}

// ---------- build xcat = [prev_y | sum ctx_part] ----------
__global__ __launch_bounds__(256)
void build_xcat(const float* __restrict__ part, const float* __restrict__ py,
                float* __restrict__ xcat)
{
  int b = blockIdx.x, t = threadIdx.x;
  f32x4 acc = {};
  #pragma unroll
  for (int c2 = 0; c2 < 16; ++c2)
    acc += *(const f32x4*)(part + (size_t)(b*16 + c2) * 1024 + t * 4);
  *(f32x4*)(xcat + b*1536 + 512 + t*4) = acc;
  if (t < 128)
    *(f32x4*)(xcat + b*1536 + t*4) = *(const f32x4*)(py + b*512 + t*4);
}

// ---------- fused: reduce gi/gh partials + biases + GRU ----------
__global__ __launch_bounds__(256)
void gru_fused(const float* __restrict__ gip, const float* __restrict__ ghp,
               const float* __restrict__ b_ih, const float* __restrict__ b_hh,
               const float* __restrict__ h, float* __restrict__ hnew)
{
  int idx = blockIdx.x * 256 + threadIdx.x;
  int b = idx >> 10, i = idx & 1023;
  float gr = b_ih[i], gz = b_ih[1024+i], gn = b_ih[2048+i];
  float hr = b_hh[i], hz = b_hh[1024+i], hn = b_hh[2048+i];
  #pragma unroll
  for (int z = 0; z < 8; ++z){
    const float* p = gip + (size_t)z*196608 + b*3072;
    gr += p[i]; gz += p[1024+i]; gn += p[2048+i];
    const float* q = ghp + (size_t)z*196608 + b*3072;
    hr += q[i]; hz += q[1024+i]; hn += q[2048+i];
  }
  float r  = sigm(gr + hr);
  float zz = sigm(gz + hz);
  float n  = tanhf(gn + r * hn);
  hnew[idx] = (1.f - zz) * n + zz * h[idx];
}

// ---------- log_softmax in-place over V ----------
__global__ __launch_bounds__(1024)
void logsoftmax_kernel(float* __restrict__ logits)
{
  __shared__ float sb[16];
  int b = blockIdx.x, t = threadIdx.x, lane = t & 63, wid = t >> 6;
  float* row = logits + (size_t)b * VOCAB;
  float v[32]; float mx = -1e30f;
  #pragma unroll
  for (int k = 0; k < 32; ++k){
    int idx = t + k * 1024;
    if (idx < VOCAB){ v[k] = row[idx]; mx = fmaxf(mx, v[k]); }
    else v[k] = -1e30f;
  }
  for (int d = 1; d < 64; d <<= 1) mx = fmaxf(mx, __shfl_xor(mx, d, 64));
  if (lane == 0) sb[wid] = mx;
  __syncthreads();
  float m2 = -1e30f;
  for (int i = 0; i < 16; ++i) m2 = fmaxf(m2, sb[i]);
  mx = m2;
  float sum = 0.f;
  #pragma unroll
  for (int k = 0; k < 32; ++k){
    int idx = t + k * 1024;
    if (idx < VOCAB) sum += expf(v[k] - mx);
  }
  for (int d = 1; d < 64; d <<= 1) sum += __shfl_xor(sum, d, 64);
  __syncthreads();
  if (lane == 0) sb[wid] = sum;
  __syncthreads();
  float s2 = 0.f;
  for (int i = 0; i < 16; ++i) s2 += sb[i];
  float lse = mx + logf(s2);
  #pragma unroll
  for (int k = 0; k < 32; ++k){
    int idx = t + k * 1024;
    if (idx < VOCAB) row[idx] = v[k] - lse;
  }
}

// ---------- launcher ----------
extern "C" void kernel_launch(void* const* d_in, const int* in_sizes, int n_in,
                              void* d_out, int out_size, void* d_ws, size_t ws_size,
                              hipStream_t stream)
{
  const float* prev_y = (const float*)d_in[0];
  const float* prev_h = (const float*)d_in[1];
  const float* enc    = (const float*)d_in[2];
  const float* U_w    = (const float*)d_in[3];
  const float* U_b    = (const float*)d_in[4];
  const float* W_w    = (const float*)d_in[5];
  const float* W_b    = (const float*)d_in[6];
  const float* v_w    = (const float*)d_in[7];
  const float* v_b    = (const float*)d_in[8];
  const float* Wc_w   = (const float*)d_in[9];
  const float* Wc_b   = (const float*)d_in[10];
  const float* W_ih   = (const float*)d_in[11];
  const float* W_hh   = (const float*)d_in[12];
  const float* b_ih   = (const float*)d_in[13];
  const float* b_hh   = (const float*)d_in[14];
  const float* Wout_w = (const float*)d_in[15];
  const float* Wout_b = (const float*)d_in[16];
  const int*   maskp  = (const int*)d_in[17];

  char* wsb = (char*)d_ws;
  const size_t ENC_B = 134217728ULL;   // 64M bf16
  const size_t UW_B  = 2097152ULL;     // 1M bf16
  const size_t FLOATS_B = 26083328ULL; // float region below
  bool big = ws_size >= ENC_B + UW_B + FLOATS_B;

  unsigned short* encb = (unsigned short*)wsb;
  unsigned short* uwb  = (unsigned short*)(wsb + ENC_B);
  float* f = (float*)(wsb + (big ? (ENC_B + UW_B) : 0));
  float* scores_part = f;                       // 16*64*1024 = 1048576  [plane][b][s]
  float* wq_part     = scores_part + 1048576;   // 8*64*1024  = 524288
  float* wq          = wq_part + 524288;        // 65536
  float* ctx_part    = wq + 65536;              // 16*64*1024 = 1048576
  float* xcat        = ctx_part + 1048576;      // 98304
  float* xvec_part   = xcat + 98304;            // 524288
  float* xvec        = xvec_part + 524288;      // 65536
  float* gi_part     = xvec + 65536;            // 8*64*3072 = 1572864
  float* gh_part     = gi_part + 1572864;       // 1572864

  float* out_logp = (float*)d_out;
  float* out_h    = out_logp + 64 * VOCAB;
  float* out_attn = out_h + 65536;

  if (big)
    convert_all<<<2048, 256, 0, stream>>>(U_w, enc, uwb, encb);

  // wq = prev_h @ W_w^T + W_b  (z-split partials + reduce)
  gemm_m64<<<dim3(8,1,8), 256, 0, stream>>>(prev_h, W_w, nullptr, nullptr, wq_part, 1024, 1024, 4);
  reduce8_bias<<<64, 256, 0, stream>>>(wq_part, W_b, wq, 1024);

  if (big)
    score_gemm_bf16<<<4096, 256, 0, stream>>>(encb, uwb, U_b, v_w, wq, maskp, scores_part);
  else
    score_gemm_f32<<<4096, 256, 0, stream>>>(enc, U_w, U_b, v_w, wq, maskp, scores_part);

  softmax_attn<<<64, 256, 0, stream>>>(scores_part, v_b, maskp, out_attn);

  if (big) ctx_bf16<<<1024, 256, 0, stream>>>(out_attn, encb, ctx_part);
  else     ctx_f32<<<1024, 256, 0, stream>>>(out_attn, enc, ctx_part);
  build_xcat<<<64, 256, 0, stream>>>(ctx_part, prev_y, xcat);

  gemm_m64<<<dim3(8,1,8), 256, 0, stream>>>(xcat, Wc_w, nullptr, nullptr, xvec_part, 1024, 1536, 6);
  reduce8_bias<<<64, 256, 0, stream>>>(xvec_part, Wc_b, xvec, 1024);

  gemm_m64<<<dim3(24,1,8), 256, 0, stream>>>(xvec, W_ih, nullptr, nullptr, gi_part, 3072, 1024, 4);
  gemm_m64<<<dim3(24,1,8), 256, 0, stream>>>(prev_h, W_hh, nullptr, nullptr, gh_part, 3072, 1024, 4);
  gru_fused<<<256, 256, 0, stream>>>(gi_part, gh_part, b_ih, b_hh, prev_h, out_h);

  gemm_m64<<<dim3(250,1,1), 256, 0, stream>>>(out_h, Wout_w, Wout_b, out_logp, nullptr, VOCAB, 1024, 32);
  logsoftmax_kernel<<<64, 1024, 0, stream>>>(out_logp);
}

// Round 8
// 743.099 us; speedup vs baseline: 1.1129x; 1.0275x over previous
//
#include <hip/hip_runtime.h>

typedef float f32x4 __attribute__((ext_vector_type(4)));
typedef short short8 __attribute__((ext_vector_type(8)));
typedef unsigned int u32;

#define SEQ   1024
#define VOCAB 32000

// ---------- helpers ----------
__device__ __forceinline__ unsigned short f2bf(float f){
  union { float f; unsigned u; } v; v.f = f;
  unsigned r = v.u + 0x7FFFu + ((v.u >> 16) & 1u);   // RNE
  return (unsigned short)(r >> 16);
}
__device__ __forceinline__ unsigned pk2(float a, float b){
  return (unsigned)f2bf(a) | ((unsigned)f2bf(b) << 16);
}
__device__ __forceinline__ float bf2f(unsigned short h){
  union { unsigned u; float f; } v; v.u = ((unsigned)h) << 16; return v.f;
}
__device__ __forceinline__ float tanh_fast(float x){
  float a = fminf(fmaxf(x, -15.f), 15.f);
  float e = __expf(2.f * a);
  return (e - 1.f) / (e + 1.f);
}
__device__ __forceinline__ float sigm(float x){ return 1.f / (1.f + expf(-x)); }

__device__ __forceinline__ void ld4(float4* dst, const float* p){
  const float4* q = (const float4*)p;
  dst[0]=q[0]; dst[1]=q[1]; dst[2]=q[2]; dst[3]=q[3];
}
__device__ __forceinline__ void cvt_store(char* base, int row, int kb0, const float4* f){
  int xs = (row & 7) << 4;
  uint4 u;
  u.x = pk2(f[0].x, f[0].y); u.y = pk2(f[0].z, f[0].w);
  u.z = pk2(f[1].x, f[1].y); u.w = pk2(f[1].z, f[1].w);
  *(uint4*)(base + row*128 + (kb0 ^ xs)) = u;
  u.x = pk2(f[2].x, f[2].y); u.y = pk2(f[2].z, f[2].w);
  u.z = pk2(f[3].x, f[3].y); u.w = pk2(f[3].z, f[3].w);
  *(uint4*)(base + row*128 + ((kb0 + 16) ^ xs)) = u;
}
// async global(16B) -> LDS, wave-uniform LDS base + lane*16
__device__ __forceinline__ void gload_lds16(const void* g, void* l){
  __builtin_amdgcn_global_load_lds((const __attribute__((address_space(1))) u32*)g,
                                   (__attribute__((address_space(3))) u32*)l, 16, 0, 0);
}

// ---------- convert U_w (1M) + enc (64M) fp32 -> bf16 ----------
__global__ __launch_bounds__(256)
void convert_all(const float* __restrict__ uw, const float* __restrict__ enc,
                 unsigned short* __restrict__ uwb, unsigned short* __restrict__ encb)
{
  const int UWC = 131072;                 // 1M/8 chunks
  const int TOT = UWC + 8388608;          // + 64M/8 chunks
  int stride = gridDim.x * 256;
  for (int c = blockIdx.x*256 + threadIdx.x; c < TOT; c += stride){
    const float* src; unsigned short* dst;
    if (c < UWC){ src = uw + (size_t)c*8;        dst = uwb + (size_t)c*8; }
    else        { size_t e = (size_t)(c-UWC)*8;  src = enc + e; dst = encb + e; }
    float4 f0 = ((const float4*)src)[0], f1 = ((const float4*)src)[1];
    uint4 u;
    u.x = pk2(f0.x,f0.y); u.y = pk2(f0.z,f0.w);
    u.z = pk2(f1.x,f1.y); u.w = pk2(f1.z,f1.w);
    *(uint4*)dst = u;
  }
}

// ---------- fused score GEMM (bf16, BK=32, 32KB dbuf, counted vmcnt, 4 blocks/CU) ----------
// scores_part[nt*2+wn][b][s] = partial of v·tanh(uh + Ub + wq) over this block's 64 A-cols
__global__ __launch_bounds__(256, 4)
void score_gemm_bf16(const unsigned short* __restrict__ encb,
                     const unsigned short* __restrict__ uwb,
                     const float* __restrict__ Ub, const float* __restrict__ vw,
                     const float* __restrict__ wqm, const int* __restrict__ maskp,
                     float* __restrict__ scores_part)
{
  __shared__ char smem[32768];           // 2 bufs x (A 8KB + B 8KB)
  int m = *maskp; m = m < 0 ? 0 : (m > SEQ ? SEQ : m);
  int bI = blockIdx.x;
  int mtile = bI & 511, ntile = bI >> 9; // same mtile -> same XCD (stride 512 ≡ 0 mod 8)
  if (mtile * 2 >= m) return;
  int t = threadIdx.x, lane = t & 63, wid = t >> 6;
  int wm = wid >> 1, wn = wid & 1;

  // staging: linear LDS dest (64B rows), swz(r) = ((r>>1)&3)<<4
  // LDS[r][c] = G[r][c ^ swz(r)] via pre-swizzled per-lane global src
  int rbase = wid*32 + (lane >> 2);      // row for instr i=0 (i=1 adds 16)
  int scol  = (((lane & 3) ^ ((lane >> 3) & 3)) << 4);
  const char* pa = (const char*)encb + (size_t)(mtile*128 + rbase)*2048 + scol;
  const char* pb = (const char*)uwb  + (size_t)(ntile*128 + rbase)*2048 + scol;

  int kb = (lane >> 4) << 4;
  int aOff[4], bOff[4];
  #pragma unroll
  for (int i = 0; i < 4; ++i){
    int ra = wm*64 + i*16 + (lane & 15);
    aOff[i] = ra*64 + (kb ^ (((ra >> 1) & 3) << 4));
    int rb = wn*64 + i*16 + (lane & 15);
    bOff[i] = rb*64 + (kb ^ (((rb >> 1) & 3) << 4));
  }
  int ldsW = wid * 2048;                 // per-wave stage offset inside 8KB region

  f32x4 acc[4][4] = {};

  // prologue: stage tile 0 into buf0 (4 loads in flight per wave)
  {
    char* dA = smem + ldsW;
    char* dB = smem + 8192 + ldsW;
    gload_lds16(pa,         dA);
    gload_lds16(pa + 32768, dA + 1024);  // +16 rows
    gload_lds16(pb,         dB);
    gload_lds16(pb + 32768, dB + 1024);
  }

  for (int ks = 0; ks < 32; ++ks){
    if (ks < 31){
      char* base = smem + ((ks+1)&1)*16384;
      char* dA = base + ldsW;
      char* dB = base + 8192 + ldsW;
      int ko = (ks+1)*64;
      gload_lds16(pa + ko,         dA);
      gload_lds16(pa + 32768 + ko, dA + 1024);
      gload_lds16(pb + ko,         dB);
      gload_lds16(pb + 32768 + ko, dB + 1024);
      asm volatile("s_waitcnt vmcnt(4)" ::: "memory");   // tile ks landed, ks+1 in flight
    } else {
      asm volatile("s_waitcnt vmcnt(0)" ::: "memory");
    }
    __builtin_amdgcn_s_barrier();        // all waves' tile-ks DMA landed
    {
      char* bufA = smem + (ks&1)*16384;
      char* bufB = bufA + 8192;
      short8 af[4], bv[4];
      #pragma unroll
      for (int i = 0; i < 4; ++i){
        af[i] = *(const short8*)(bufA + aOff[i]);
        bv[i] = *(const short8*)(bufB + bOff[i]);
      }
      #pragma unroll
      for (int mi = 0; mi < 4; ++mi)
        #pragma unroll
        for (int ni = 0; ni < 4; ++ni)
          acc[mi][ni] = __builtin_amdgcn_mfma_f32_16x16x32_bf16(af[mi], bv[ni], acc[mi][ni], 0, 0, 0);
    }
    __builtin_amdgcn_s_barrier();        // reads of buf done before next overwrite
  }

  int s_idx = mtile * 2 + wm;            // each wave owns one s (its 64 rows = 64 b)
  if (s_idx < m){
    float ubv[4], vwv[4];
    #pragma unroll
    for (int ni = 0; ni < 4; ++ni){
      int nt = ntile*128 + wn*64 + ni*16 + (lane & 15);
      ubv[ni] = Ub[nt]; vwv[ni] = vw[nt];
    }
    #pragma unroll
    for (int mi = 0; mi < 4; ++mi){
      #pragma unroll
      for (int j = 0; j < 4; ++j){
        int b = mi*16 + ((lane >> 4) << 2) + j;   // C/D: col=lane&15, row=(lane>>4)*4+j
        const float* wqrow = wqm + b * 1024;
        float asum = 0.f;
        #pragma unroll
        for (int ni = 0; ni < 4; ++ni){
          int nt = ntile*128 + wn*64 + ni*16 + (lane & 15);
          float uh = acc[mi][ni][j] + ubv[ni] + wqrow[nt];
          asum += tanh_fast(uh) * vwv[ni];
        }
        asum += __shfl_xor(asum, 1, 64);
        asum += __shfl_xor(asum, 2, 64);
        asum += __shfl_xor(asum, 4, 64);
        asum += __shfl_xor(asum, 8, 64);
        if ((lane & 15) == 0)
          scores_part[(ntile*2 + wn)*65536 + b*1024 + s_idx] = asum;   // [plane][b][s]
      }
    }
  }
}

// ---------- fallback score GEMM (fp32 inputs, in-kernel cvt) ----------
__global__ __launch_bounds__(256, 2)
void score_gemm_f32(const float* __restrict__ enc, const float* __restrict__ Uw,
                    const float* __restrict__ Ub, const float* __restrict__ vw,
                    const float* __restrict__ wqm, const int* __restrict__ maskp,
                    float* __restrict__ scores_part)
{
  __shared__ char smem[65536];
  int m = *maskp; m = m < 0 ? 0 : (m > SEQ ? SEQ : m);
  int bI = blockIdx.x;
  int mtile = bI & 511, ntile = bI >> 9;
  if (mtile * 2 >= m) return;
  int row0 = mtile * 128;
  int t = threadIdx.x, lane = t & 63;
  int wid = t >> 6, wm = wid >> 1, wn = wid & 1;
  int srow = t >> 2;
  int sk4 = (t & 3) << 4;
  int kb0 = (t & 3) << 5;

  const float* Ag0 = enc + (size_t)(row0 + srow) * 1024 + sk4;
  const float* Ag1 = Ag0 + 64 * 1024;
  const float* Bg0 = Uw  + (size_t)(ntile * 128 + srow) * 1024 + sk4;
  const float* Bg1 = Bg0 + 64 * 1024;

  float4 fa0[4], fa1[4], fb0[4], fb1[4];
  int aAddr[4], bAddr[4], aXor[4], bXor[4];
  #pragma unroll
  for (int i = 0; i < 4; ++i){
    int ra = wm*64 + i*16 + (lane & 15);
    aAddr[i] = ra * 128; aXor[i] = (ra & 7) << 4;
    int rb = wn*64 + i*16 + (lane & 15);
    bAddr[i] = rb * 128; bXor[i] = (rb & 7) << 4;
  }
  int klane = (lane >> 4) << 4;
  f32x4 acc[4][4] = {};

  ld4(fa0, Ag0); ld4(fa1, Ag1); ld4(fb0, Bg0); ld4(fb1, Bg1);
  {
    char* bA = smem; char* bB = smem + 16384;
    cvt_store(bA, srow,      kb0, fa0);
    cvt_store(bA, srow + 64, kb0, fa1);
    cvt_store(bB, srow,      kb0, fb0);
    cvt_store(bB, srow + 64, kb0, fb1);
  }
  #pragma unroll 2
  for (int ks = 0; ks < 16; ++ks){
    int buf = ks & 1;
    if (ks < 15){
      int ko = (ks + 1) * 64;
      ld4(fa0, Ag0 + ko); ld4(fa1, Ag1 + ko);
      ld4(fb0, Bg0 + ko); ld4(fb1, Bg1 + ko);
    }
    __syncthreads();
    {
      char* bA = smem + buf * 32768;
      char* bB = bA + 16384;
      #pragma unroll
      for (int kk = 0; kk < 2; ++kk){
        short8 af[4], bv[4];
        int kb = kk * 64 + klane;
        #pragma unroll
        for (int i = 0; i < 4; ++i){
          af[i] = *(const short8*)(bA + aAddr[i] + (kb ^ aXor[i]));
          bv[i] = *(const short8*)(bB + bAddr[i] + (kb ^ bXor[i]));
        }
        #pragma unroll
        for (int mi = 0; mi < 4; ++mi)
          #pragma unroll
          for (int ni = 0; ni < 4; ++ni)
            acc[mi][ni] = __builtin_amdgcn_mfma_f32_16x16x32_bf16(af[mi], bv[ni], acc[mi][ni], 0, 0, 0);
      }
    }
    if (ks < 15){
      int nb = buf ^ 1;
      char* bA = smem + nb * 32768; char* bB = bA + 16384;
      cvt_store(bA, srow,      kb0, fa0);
      cvt_store(bA, srow + 64, kb0, fa1);
      cvt_store(bB, srow,      kb0, fb0);
      cvt_store(bB, srow + 64, kb0, fb1);
    }
  }

  int s_idx = mtile * 2 + wm;
  if (s_idx < m){
    float ubv[4], vwv[4];
    #pragma unroll
    for (int ni = 0; ni < 4; ++ni){
      int nt = ntile*128 + wn*64 + ni*16 + (lane & 15);
      ubv[ni] = Ub[nt]; vwv[ni] = vw[nt];
    }
    #pragma unroll
    for (int mi = 0; mi < 4; ++mi){
      #pragma unroll
      for (int j = 0; j < 4; ++j){
        int b = mi*16 + ((lane >> 4) << 2) + j;
        const float* wqrow = wqm + b * 1024;
        float asum = 0.f;
        #pragma unroll
        for (int ni = 0; ni < 4; ++ni){
          int nt = ntile*128 + wn*64 + ni*16 + (lane & 15);
          float uh = acc[mi][ni][j] + ubv[ni] + wqrow[nt];
          asum += tanh_fast(uh) * vwv[ni];
        }
        asum += __shfl_xor(asum, 1, 64);
        asum += __shfl_xor(asum, 2, 64);
        asum += __shfl_xor(asum, 4, 64);
        asum += __shfl_xor(asum, 8, 64);
        if ((lane & 15) == 0)
          scores_part[(ntile*2 + wn)*65536 + b*1024 + s_idx] = asum;   // [plane][b][s]
      }
    }
  }
}

// ---------- small GEMM: C[64,N] = A[64,K] @ B[N,K]^T, bf16 MFMA ----------
// gridDim.z>1: write z-partials to Cpart[z][64][N] (no bias); else direct + bias
__global__ __launch_bounds__(256)
void gemm_m64(const float* __restrict__ A, const float* __restrict__ Bw,
              const float* __restrict__ bias, float* __restrict__ C,
              float* __restrict__ Cpart, int N, int K, int stepsPerZ)
{
  __shared__ unsigned short sA[2][64 * 40];
  __shared__ unsigned short sB[2][128 * 40];
  int t = threadIdx.x, lane = t & 63, wid = t >> 6;
  int ntile = blockIdx.x, z = blockIdx.z;
  int arow = t >> 2, ak = (t & 3) * 8;
  int brow = t >> 1, bk = (t & 1) * 16;
  const float* Ap = A + (size_t)arow * K + ak + (size_t)z * stepsPerZ * 32;
  const float* Bp = Bw + (size_t)(ntile * 128 + brow) * K + bk + (size_t)z * stepsPerZ * 32;
  int klane = (lane >> 4) << 4;
  f32x4 acc[4][2] = {};
  float4 a0, a1, b0, b1, b2, b3;

  {
    const float4* pa = (const float4*)Ap;
    a0 = pa[0]; a1 = pa[1];
    const float4* pb = (const float4*)Bp;
    b0 = pb[0]; b1 = pb[1]; b2 = pb[2]; b3 = pb[3];
    uint4 u;
    u.x = pk2(a0.x,a0.y); u.y = pk2(a0.z,a0.w);
    u.z = pk2(a1.x,a1.y); u.w = pk2(a1.z,a1.w);
    *(uint4*)((char*)sA[0] + arow*80 + ak*2) = u;
    u.x = pk2(b0.x,b0.y); u.y = pk2(b0.z,b0.w);
    u.z = pk2(b1.x,b1.y); u.w = pk2(b1.z,b1.w);
    *(uint4*)((char*)sB[0] + brow*80 + bk*2) = u;
    u.x = pk2(b2.x,b2.y); u.y = pk2(b2.z,b2.w);
    u.z = pk2(b3.x,b3.y); u.w = pk2(b3.z,b3.w);
    *(uint4*)((char*)sB[0] + brow*80 + bk*2 + 16) = u;
  }

  for (int ks = 0; ks < stepsPerZ; ++ks){
    int buf = ks & 1;
    if (ks + 1 < stepsPerZ){
      int kg = (ks + 1) * 32;
      const float4* pa = (const float4*)(Ap + kg);
      a0 = pa[0]; a1 = pa[1];
      const float4* pb = (const float4*)(Bp + kg);
      b0 = pb[0]; b1 = pb[1]; b2 = pb[2]; b3 = pb[3];
    }
    __syncthreads();
    {
      short8 af[4], bv[2];
      #pragma unroll
      for (int mi = 0; mi < 4; ++mi)
        af[mi] = *(const short8*)((char*)sA[buf] + (mi*16 + (lane & 15))*80 + klane);
      #pragma unroll
      for (int ni = 0; ni < 2; ++ni)
        bv[ni] = *(const short8*)((char*)sB[buf] + (wid*32 + ni*16 + (lane & 15))*80 + klane);
      #pragma unroll
      for (int mi = 0; mi < 4; ++mi)
        #pragma unroll
        for (int ni = 0; ni < 2; ++ni)
          acc[mi][ni] = __builtin_amdgcn_mfma_f32_16x16x32_bf16(af[mi], bv[ni], acc[mi][ni], 0, 0, 0);
    }
    if (ks + 1 < stepsPerZ){
      int nb = buf ^ 1;
      uint4 u;
      u.x = pk2(a0.x,a0.y); u.y = pk2(a0.z,a0.w);
      u.z = pk2(a1.x,a1.y); u.w = pk2(a1.z,a1.w);
      *(uint4*)((char*)sA[nb] + arow*80 + ak*2) = u;
      u.x = pk2(b0.x,b0.y); u.y = pk2(b0.z,b0.w);
      u.z = pk2(b1.x,b1.y); u.w = pk2(b1.z,b1.w);
      *(uint4*)((char*)sB[nb] + brow*80 + bk*2) = u;
      u.x = pk2(b2.x,b2.y); u.y = pk2(b2.z,b2.w);
      u.z = pk2(b3.x,b3.y); u.w = pk2(b3.z,b3.w);
      *(uint4*)((char*)sB[nb] + brow*80 + bk*2 + 16) = u;
    }
  }

  bool multi = (gridDim.z > 1);
  #pragma unroll
  for (int ni = 0; ni < 2; ++ni){
    int cg = ntile*128 + wid*32 + ni*16 + (lane & 15);
    float bz = (bias && !multi) ? bias[cg] : 0.f;
    #pragma unroll
    for (int mi = 0; mi < 4; ++mi){
      int r0 = mi*16 + ((lane >> 4) << 2);
      #pragma unroll
      for (int j = 0; j < 4; ++j){
        float val = acc[mi][ni][j] + bz;
        if (multi) Cpart[((size_t)z*64 + r0 + j)*N + cg] = val;
        else       C[(size_t)(r0 + j)*N + cg] = val;
      }
    }
  }
}

// ---------- reduce 8 z-partials + bias ----------
__global__ __launch_bounds__(256)
void reduce8_bias(const float* __restrict__ part, const float* __restrict__ bias,
                  float* __restrict__ out, int N)
{
  int idx = blockIdx.x*256 + threadIdx.x;       // one f32x4 per thread
  int r = idx / (N >> 2), c4 = (idx % (N >> 2)) * 4;
  f32x4 acc = *(const f32x4*)(bias + c4);
  #pragma unroll
  for (int z = 0; z < 8; ++z)
    acc += *(const f32x4*)(part + ((size_t)z*64 + r)*N + c4);
  *(f32x4*)(out + (size_t)r*N + c4) = acc;
}

// ---------- softmax over S (sums 16 score partials, [plane][b][s] layout) ----------
__global__ __launch_bounds__(256)
void softmax_attn(const float* __restrict__ sp, const float* __restrict__ vb,
                  const int* __restrict__ maskp, float* __restrict__ attn)
{
  __shared__ float sb[4];
  int b = blockIdx.x, t = threadIdx.x, lane = t & 63, wid = t >> 6;
  int m = *maskp; m = m < 0 ? 0 : (m > SEQ ? SEQ : m);
  float vb0 = vb[0];
  float v[4]; float mx = -1e30f;
  #pragma unroll
  for (int k = 0; k < 4; ++k){
    int s = t + k * 256;
    float x = 0.f;
    if (s < m){
      float a = 0.f;
      #pragma unroll
      for (int p = 0; p < 16; ++p) a += sp[p*65536 + b*1024 + s];
      x = a + vb0;
    }
    v[k] = x; mx = fmaxf(mx, x);
  }
  for (int d = 1; d < 64; d <<= 1) mx = fmaxf(mx, __shfl_xor(mx, d, 64));
  if (lane == 0) sb[wid] = mx;
  __syncthreads();
  mx = fmaxf(fmaxf(sb[0], sb[1]), fmaxf(sb[2], sb[3]));
  float sum = 0.f;
  #pragma unroll
  for (int k = 0; k < 4; ++k){ v[k] = expf(v[k] - mx); sum += v[k]; }
  for (int d = 1; d < 64; d <<= 1) sum += __shfl_xor(sum, d, 64);
  __syncthreads();
  if (lane == 0) sb[wid] = sum;
  __syncthreads();
  sum = sb[0] + sb[1] + sb[2] + sb[3];
  #pragma unroll
  for (int k = 0; k < 4; ++k) attn[b*1024 + t + k*256] = v[k] / sum;
}

// ---------- ctx partials (bf16 enc) ----------
__global__ __launch_bounds__(256)
void ctx_bf16(const float* __restrict__ attn, const unsigned short* __restrict__ encb,
              float* __restrict__ ctx_part)
{
  int b = blockIdx.x >> 4, ch = blockIdx.x & 15;
  int t = threadIdx.x;
  __shared__ float a_s[64];
  if (t < 64) a_s[t] = attn[b*1024 + ch*64 + t];
  __syncthreads();
  const unsigned short* base = encb + ((size_t)(ch*64)*64 + b)*1024 + t*4;
  f32x4 acc = {};
  for (int s2 = 0; s2 < 64; ++s2){
    ushort4 vv = *(const ushort4*)(base + (size_t)s2*65536);
    float w = a_s[s2];
    acc.x += w * bf2f(vv.x); acc.y += w * bf2f(vv.y);
    acc.z += w * bf2f(vv.z); acc.w += w * bf2f(vv.w);
  }
  *(f32x4*)(ctx_part + (size_t)(b*16 + ch)*1024 + t*4) = acc;
}

// ---------- ctx partials (fp32 enc, fallback) ----------
__global__ __launch_bounds__(256)
void ctx_f32(const float* __restrict__ attn, const float* __restrict__ enc,
             float* __restrict__ ctx_part)
{
  int b = blockIdx.x >> 4, ch = blockIdx.x & 15;
  int t = threadIdx.x;
  __shared__ float a_s[64];
  if (t < 64) a_s[t] = attn[b*1024 + ch*64 + t];
  __syncthreads();
  const float* ep = enc + (size_t)(ch * 64) * 65536 + b * 1024 + t * 4;
  f32x4 acc = {};
  for (int s2 = 0; s2 < 64; ++s2){
    f32x4 v = *(const f32x4*)(ep + (size_t)s2 * 65536);
    acc += a_s[s2] * v;
  }
  *(f32x4*)(ctx_part + (size_t)(b*16 + ch)*1024 + t*4) = acc;
}

// ---------- build xcat = [prev_y | sum ctx_part] ----------
__global__ __launch_bounds__(256)
void build_xcat(const float* __restrict__ part, const float* __restrict__ py,
                float* __restrict__ xcat)
{
  int b = blockIdx.x, t = threadIdx.x;
  f32x4 acc = {};
  #pragma unroll
  for (int c2 = 0; c2 < 16; ++c2)
    acc += *(const f32x4*)(part + (size_t)(b*16 + c2) * 1024 + t * 4);
  *(f32x4*)(xcat + b*1536 + 512 + t*4) = acc;
  if (t < 128)
    *(f32x4*)(xcat + b*1536 + t*4) = *(const f32x4*)(py + b*512 + t*4);
}

// ---------- fused: reduce gi/gh partials + biases + GRU ----------
__global__ __launch_bounds__(256)
void gru_fused(const float* __restrict__ gip, const float* __restrict__ ghp,
               const float* __restrict__ b_ih, const float* __restrict__ b_hh,
               const float* __restrict__ h, float* __restrict__ hnew)
{
  int idx = blockIdx.x * 256 + threadIdx.x;
  int b = idx >> 10, i = idx & 1023;
  float gr = b_ih[i], gz = b_ih[1024+i], gn = b_ih[2048+i];
  float hr = b_hh[i], hz = b_hh[1024+i], hn = b_hh[2048+i];
  #pragma unroll
  for (int z = 0; z < 8; ++z){
    const float* p = gip + (size_t)z*196608 + b*3072;
    gr += p[i]; gz += p[1024+i]; gn += p[2048+i];
    const float* q = ghp + (size_t)z*196608 + b*3072;
    hr += q[i]; hz += q[1024+i]; hn += q[2048+i];
  }
  float r  = sigm(gr + hr);
  float zz = sigm(gz + hz);
  float n  = tanhf(gn + r * hn);
  hnew[idx] = (1.f - zz) * n + zz * h[idx];
}

// ---------- log_softmax reading 4 Wout z-partials + bias ----------
__global__ __launch_bounds__(1024)
void logsoftmax_fused4(const float* __restrict__ part, const float* __restrict__ bias,
                       float* __restrict__ out)
{
  __shared__ float sb[16];
  int b = blockIdx.x, t = threadIdx.x, lane = t & 63, wid = t >> 6;
  float v[32]; float mx = -1e30f;
  #pragma unroll
  for (int k = 0; k < 32; ++k){
    int idx = t + k * 1024;
    if (idx < VOCAB){
      float x = bias[idx];
      #pragma unroll
      for (int z = 0; z < 4; ++z) x += part[((size_t)(z*64 + b))*VOCAB + idx];
      v[k] = x; mx = fmaxf(mx, x);
    } else v[k] = -1e30f;
  }
  for (int d = 1; d < 64; d <<= 1) mx = fmaxf(mx, __shfl_xor(mx, d, 64));
  if (lane == 0) sb[wid] = mx;
  __syncthreads();
  float m2 = -1e30f;
  for (int i = 0; i < 16; ++i) m2 = fmaxf(m2, sb[i]);
  mx = m2;
  float sum = 0.f;
  #pragma unroll
  for (int k = 0; k < 32; ++k){
    int idx = t + k * 1024;
    if (idx < VOCAB) sum += expf(v[k] - mx);
  }
  for (int d = 1; d < 64; d <<= 1) sum += __shfl_xor(sum, d, 64);
  __syncthreads();
  if (lane == 0) sb[wid] = sum;
  __syncthreads();
  float s2 = 0.f;
  for (int i = 0; i < 16; ++i) s2 += sb[i];
  float lse = mx + logf(s2);
  float* row = out + (size_t)b * VOCAB;
  #pragma unroll
  for (int k = 0; k < 32; ++k){
    int idx = t + k * 1024;
    if (idx < VOCAB) row[idx] = v[k] - lse;
  }
}

// ---------- log_softmax in-place over V (fallback) ----------
__global__ __launch_bounds__(1024)
void logsoftmax_kernel(float* __restrict__ logits)
{
  __shared__ float sb[16];
  int b = blockIdx.x, t = threadIdx.x, lane = t & 63, wid = t >> 6;
  float* row = logits + (size_t)b * VOCAB;
  float v[32]; float mx = -1e30f;
  #pragma unroll
  for (int k = 0; k < 32; ++k){
    int idx = t + k * 1024;
    if (idx < VOCAB){ v[k] = row[idx]; mx = fmaxf(mx, v[k]); }
    else v[k] = -1e30f;
  }
  for (int d = 1; d < 64; d <<= 1) mx = fmaxf(mx, __shfl_xor(mx, d, 64));
  if (lane == 0) sb[wid] = mx;
  __syncthreads();
  float m2 = -1e30f;
  for (int i = 0; i < 16; ++i) m2 = fmaxf(m2, sb[i]);
  mx = m2;
  float sum = 0.f;
  #pragma unroll
  for (int k = 0; k < 32; ++k){
    int idx = t + k * 1024;
    if (idx < VOCAB) sum += expf(v[k] - mx);
  }
  for (int d = 1; d < 64; d <<= 1) sum += __shfl_xor(sum, d, 64);
  __syncthreads();
  if (lane == 0) sb[wid] = sum;
  __syncthreads();
  float s2 = 0.f;
  for (int i = 0; i < 16; ++i) s2 += sb[i];
  float lse = mx + logf(s2);
  #pragma unroll
  for (int k = 0; k < 32; ++k){
    int idx = t + k * 1024;
    if (idx < VOCAB) row[idx] = v[k] - lse;
  }
}

// ---------- launcher ----------
extern "C" void kernel_launch(void* const* d_in, const int* in_sizes, int n_in,
                              void* d_out, int out_size, void* d_ws, size_t ws_size,
                              hipStream_t stream)
{
  const float* prev_y = (const float*)d_in[0];
  const float* prev_h = (const float*)d_in[1];
  const float* enc    = (const float*)d_in[2];
  const float* U_w    = (const float*)d_in[3];
  const float* U_b    = (const float*)d_in[4];
  const float* W_w    = (const float*)d_in[5];
  const float* W_b    = (const float*)d_in[6];
  const float* v_w    = (const float*)d_in[7];
  const float* v_b    = (const float*)d_in[8];
  const float* Wc_w   = (const float*)d_in[9];
  const float* Wc_b   = (const float*)d_in[10];
  const float* W_ih   = (const float*)d_in[11];
  const float* W_hh   = (const float*)d_in[12];
  const float* b_ih   = (const float*)d_in[13];
  const float* b_hh   = (const float*)d_in[14];
  const float* Wout_w = (const float*)d_in[15];
  const float* Wout_b = (const float*)d_in[16];
  const int*   maskp  = (const int*)d_in[17];

  char* wsb = (char*)d_ws;
  const size_t ENC_B    = 134217728ULL;  // 64M bf16
  const size_t UW_B     = 2097152ULL;    // 1M bf16
  const size_t FLOATS1_B = 26083328ULL;  // float region w/o wout_part
  const size_t FLOATS2_B = FLOATS1_B + 32768000ULL; // + 4*64*32000*4
  bool big  = ws_size >= ENC_B + UW_B + FLOATS1_B;
  bool big2 = ws_size >= ENC_B + UW_B + FLOATS2_B;

  unsigned short* encb = (unsigned short*)wsb;
  unsigned short* uwb  = (unsigned short*)(wsb + ENC_B);
  float* f = (float*)(wsb + (big ? (ENC_B + UW_B) : 0));
  float* scores_part = f;                       // 16*64*1024 = 1048576  [plane][b][s]
  float* wq_part     = scores_part + 1048576;   // 8*64*1024  = 524288
  float* wq          = wq_part + 524288;        // 65536
  float* ctx_part    = wq + 65536;              // 16*64*1024 = 1048576
  float* xcat        = ctx_part + 1048576;      // 98304
  float* xvec_part   = xcat + 98304;            // 524288
  float* xvec        = xvec_part + 524288;      // 65536
  float* gi_part     = xvec + 65536;            // 8*64*3072 = 1572864
  float* gh_part     = gi_part + 1572864;       // 1572864
  float* wout_part   = gh_part + 1572864;       // 4*64*32000 = 8192000 (big2 only)

  float* out_logp = (float*)d_out;
  float* out_h    = out_logp + 64 * VOCAB;
  float* out_attn = out_h + 65536;

  if (big)
    convert_all<<<2048, 256, 0, stream>>>(U_w, enc, uwb, encb);

  // wq = prev_h @ W_w^T + W_b  (z-split partials + reduce)
  gemm_m64<<<dim3(8,1,8), 256, 0, stream>>>(prev_h, W_w, nullptr, nullptr, wq_part, 1024, 1024, 4);
  reduce8_bias<<<64, 256, 0, stream>>>(wq_part, W_b, wq, 1024);

  if (big)
    score_gemm_bf16<<<4096, 256, 0, stream>>>(encb, uwb, U_b, v_w, wq, maskp, scores_part);
  else
    score_gemm_f32<<<4096, 256, 0, stream>>>(enc, U_w, U_b, v_w, wq, maskp, scores_part);

  softmax_attn<<<64, 256, 0, stream>>>(scores_part, v_b, maskp, out_attn);

  if (big) ctx_bf16<<<1024, 256, 0, stream>>>(out_attn, encb, ctx_part);
  else     ctx_f32<<<1024, 256, 0, stream>>>(out_attn, enc, ctx_part);
  build_xcat<<<64, 256, 0, stream>>>(ctx_part, prev_y, xcat);

  gemm_m64<<<dim3(8,1,8), 256, 0, stream>>>(xcat, Wc_w, nullptr, nullptr, xvec_part, 1024, 1536, 6);
  reduce8_bias<<<64, 256, 0, stream>>>(xvec_part, Wc_b, xvec, 1024);

  gemm_m64<<<dim3(24,1,8), 256, 0, stream>>>(xvec, W_ih, nullptr, nullptr, gi_part, 3072, 1024, 4);
  gemm_m64<<<dim3(24,1,8), 256, 0, stream>>>(prev_h, W_hh, nullptr, nullptr, gh_part, 3072, 1024, 4);
  gru_fused<<<256, 256, 0, stream>>>(gi_part, gh_part, b_ih, b_hh, prev_h, out_h);

  if (big2){
    gemm_m64<<<dim3(250,1,4), 256, 0, stream>>>(out_h, Wout_w, nullptr, nullptr, wout_part, VOCAB, 1024, 8);
    logsoftmax_fused4<<<64, 1024, 0, stream>>>(wout_part, Wout_b, out_logp);
  } else {
    gemm_m64<<<dim3(250,1,1), 256, 0, stream>>>(out_h, Wout_w, Wout_b, out_logp, nullptr, VOCAB, 1024, 32);
    logsoftmax_kernel<<<64, 1024, 0, stream>>>(out_logp);
  }
}